// Round 8
// baseline (20864.517 us; speedup 1.0000x reference)
//
#include <hip/hip_runtime.h>
#include <cstdint>
#include <cstddef>

// Problem constants
#define BB 256     // batch
#define TT 512     // time steps
#define HH 512     // hidden
// 256 blocks = 4 m-groups (64 rows) x 64 s-slices (8 hcols = 32 gatecols/layer), 512 thr.
// R8 = R7 + fragment-address fix: hfrag now includes the per-lane k-group offset kg
// (R7 loaded the kg=0 slice for all lanes -> bounded-wrong output).
// Barrier-free GEMMs: A-fragments loaded per-wave directly from global/regs in MFMA
// fragment layout (lane = row mu*16+ra, k = chunk + kg + j). Blocked h layout
// [par][m][slice][row][8] gives contiguous publishes (1KB/block) and contiguous
// fragment reads (256B per 16 lanes). h0 frags loaded at L1 ARE L0(t+1)'s h0_prev;
// h1 frags loaded for Q(t-1) ARE L1(t)'s h1_prev. 7 barriers/step.
// Flags: relaxed agent atomics + vmcnt(0)+syncthreads before add.

typedef _Float16 f16;
typedef _Float16 f16x8 __attribute__((ext_vector_type(8)));
typedef float f32x4 __attribute__((ext_vector_type(4)));

union U16B { uint64_t u[2]; f16x8 v; };

// ---------------- threefry2x32 (key = (0,42)), jax_threefry_partitionable ----------------
__device__ __forceinline__ void tf_round(uint32_t& x0, uint32_t& x1, const int r) {
  x0 += x1;
  x1 = (x1 << r) | (x1 >> (32 - r));
  x1 ^= x0;
}

__device__ __forceinline__ void threefry2x32(uint32_t c0, uint32_t c1, uint32_t& o0, uint32_t& o1) {
  const uint32_t ks0 = 0u, ks1 = 42u;
  const uint32_t ks2 = 0x1BD11BDAu ^ ks0 ^ ks1;
  uint32_t x0 = c0 + ks0, x1 = c1 + ks1;
  tf_round(x0,x1,13); tf_round(x0,x1,15); tf_round(x0,x1,26); tf_round(x0,x1,6);
  x0 += ks1; x1 += ks2 + 1u;
  tf_round(x0,x1,17); tf_round(x0,x1,29); tf_round(x0,x1,16); tf_round(x0,x1,24);
  x0 += ks2; x1 += ks0 + 2u;
  tf_round(x0,x1,13); tf_round(x0,x1,15); tf_round(x0,x1,26); tf_round(x0,x1,6);
  x0 += ks0; x1 += ks1 + 3u;
  tf_round(x0,x1,17); tf_round(x0,x1,29); tf_round(x0,x1,16); tf_round(x0,x1,24);
  x0 += ks1; x1 += ks2 + 4u;
  tf_round(x0,x1,13); tf_round(x0,x1,15); tf_round(x0,x1,26); tf_round(x0,x1,6);
  x0 += ks2; x1 += ks0 + 5u;
  o0 = x0; o1 = x1;
}

__device__ __forceinline__ float gumbel_noise(uint32_t idx) {
  uint32_t o0, o1;
  threefry2x32(0u, idx, o0, o1);
  uint32_t bits = o0 ^ o1;
  uint32_t fb = (bits >> 9) | 0x3f800000u;
  float u = __uint_as_float(fb) - 1.0f;
  const float tiny = 1.17549435e-38f;
  u = fmaxf(tiny, u + tiny);
  return -logf(-logf(u));
}

// ---------------- fast transcendentals (err ~1e-6, tolerance 2e-2) ----------------
__device__ __forceinline__ float fsig(float x) {
  return __builtin_amdgcn_rcpf(1.0f + __expf(-x));
}
__device__ __forceinline__ float ftanh(float x) {
  float xx = fminf(fmaxf(x, -15.f), 15.f);
  float t = __expf(2.f * xx);
  return (t - 1.f) * __builtin_amdgcn_rcpf(t + 1.f);
}

// ---------------- atomics (relaxed agent = coherence-point direct) ----------------
__device__ __forceinline__ uint64_t aload64(const f16* p) {
  return __hip_atomic_load((const uint64_t*)p, __ATOMIC_RELAXED, __HIP_MEMORY_SCOPE_AGENT);
}
__device__ __forceinline__ void astore32(uint32_t* p, uint32_t v) {
  __hip_atomic_store(p, v, __ATOMIC_RELAXED, __HIP_MEMORY_SCOPE_AGENT);
}
__device__ __forceinline__ void flag_add_relaxed(uint32_t* p) {
  __hip_atomic_fetch_add(p, 1u, __ATOMIC_RELAXED, __HIP_MEMORY_SCOPE_AGENT);
}

__device__ __forceinline__ f16x8 cvt8(f32x4 a, f32x4 b) {
  f16x8 w;
  w[0]=(f16)a[0]; w[1]=(f16)a[1]; w[2]=(f16)a[2]; w[3]=(f16)a[3];
  w[4]=(f16)b[0]; w[5]=(f16)b[1]; w[6]=(f16)b[2]; w[7]=(f16)b[3];
  return w;
}

// MFMA pair on a 64-k chunk: AE covers k..k+31, AO k+32..k+63 (per-lane 8 f16 each)
#define MFMA_PAIR(AE, AO, WROW, KOFF) { \
  f16x8 be_ = *(const f16x8*)&(WROW)[(KOFF) + kg]; \
  f16x8 bo_ = *(const f16x8*)&(WROW)[(KOFF) + 32 + kg]; \
  acce = __builtin_amdgcn_mfma_f32_16x16x32_f16((AE), be_, acce, 0, 0, 0); \
  acco = __builtin_amdgcn_mfma_f32_16x16x32_f16((AO), bo_, acco, 0, 0, 0); }

// ---------------- the persistent kernel ----------------
template<bool PRE>
__global__ __launch_bounds__(512, 1) void persistent_kernel(
    const float* __restrict__ states,
    const float* __restrict__ Wih0, const float* __restrict__ Whh0,
    const float* __restrict__ bih0, const float* __restrict__ bhh0,
    const float* __restrict__ Wih1, const float* __restrict__ Whh1,
    const float* __restrict__ bih1, const float* __restrict__ bhh1,
    const float* __restrict__ Wlin, const float* __restrict__ blin,
    float* __restrict__ out,
    uint32_t* cnt0, uint32_t* cntA, uint32_t* cntB,
    f16* h0blk, f16* h1blk, f16* Wlc, float* noise_pre)
{
  __shared__ __align__(16) f16 W0s[32][904];    // 57,856 B
  __shared__ __align__(16) f16 W1s[32][1032];   // 66,048 B
  __shared__ __align__(16) f16 ctl[64][136];    // 17,408 B
  __shared__ float glds[64][37];                //  9,472 B
  __shared__ float bls[2][4][8];                //    256 B   (total ~151 KB)

  const int tid = threadIdx.x;
  const int bid = blockIdx.x;
  const int m = bid & 3;            // m-group (64 batch rows)
  const int s = bid >> 2;           // h-col slice 0..63 (8 cols)
  const int lane = tid & 63;
  const int wv = tid >> 6;
  const int mu = wv >> 1;           // 16-row tile 0..3
  const int nu = wv & 1;            // 16-gatecol tile (Q: 64-col tile)
  const int ra = lane & 15;
  const int kg = (lane >> 4) << 3;
  const int crow = (lane >> 4) << 2;
  const int arow = mu * 16 + ra;    // this lane's A-fragment row (local 0..63)
  const int erow = tid >> 2;        // cell row (tid<256)
  const int hc2 = tid & 3;          // cell hcol pair index

  // ---- one-time LDS W init (f32 -> f16, reordered K) ----
  {
    const int lc = tid & 31;
    const int gr = ((lc >> 3) << 9) + s*8 + (lc & 7);   // gate*512 + hcol
    for (int k = tid >> 5; k < 896; k += 16) {
      float v;
      if (k < 256)      v = Wih0[(size_t)gr * 384 + k];              // x
      else if (k < 768) v = Whh0[(size_t)gr * 512 + (k - 256)];      // h0_prev
      else              v = Wih0[(size_t)gr * 384 + 256 + (k - 768)];// ct
      W0s[lc][k] = (f16)v;
    }
    for (int k = tid >> 5; k < 1024; k += 16) {
      float v = (k < 512) ? Whh1[(size_t)gr * 512 + k]               // h1_prev
                          : Wih1[(size_t)gr * 512 + (k - 512)];      // h0_cur
      W1s[lc][k] = (f16)v;
    }
  }
  for (int e = tid; e < 64 * 128; e += 512)
    ctl[e >> 7][e & 127] = (f16)(((e & 15) == 0) ? 1.f : 0.f);
  if (tid < 64) {                    // biases -> LDS: bls[layer][gate][hc]
    const int l = tid >> 5, g = (tid >> 3) & 3, hc = tid & 7;
    const int col = g * 512 + s*8 + hc;
    bls[l][g][hc] = l ? (bih1[col] + bhh1[col]) : (bih0[col] + bhh0[col]);
  }

  // ---- global init: Wlc + noise (plain stores; flushed by the startup RELEASE) ----
  if (tid < 128) {
    const int e2 = bid * 128 + tid;
    union { f16 h[2]; uint32_t u; } pk2;
    pk2.h[0] = (f16)Wlin[2*e2]; pk2.h[1] = (f16)Wlin[2*e2 + 1];
    ((uint32_t*)Wlc)[e2] = pk2.u;
  }
  if (PRE) {
    const uint32_t base = (uint32_t)bid * 65536u;
    for (uint32_t e = tid; e < 65536u; e += 512u)
      noise_pre[base + e] = gumbel_noise(base + e);
  }
  // ---- startup barrier: the ONLY cache-maintaining release/acquire ----
  __syncthreads();
  if (tid == 0) {
    __hip_atomic_fetch_add(cnt0, 1u, __ATOMIC_RELEASE, __HIP_MEMORY_SCOPE_AGENT);
    int g = 0;
    while (__hip_atomic_load(cnt0, __ATOMIC_RELAXED, __HIP_MEMORY_SCOPE_AGENT) < 256u && g < 2000000) {
      __builtin_amdgcn_s_sleep(1); ++g;
    }
    (void)__hip_atomic_load(cnt0, __ATOMIC_ACQUIRE, __HIP_MEMORY_SCOPE_AGENT);
  }
  __syncthreads();

  // ---- per-thread constants / state ----
  float blv[4];
  #pragma unroll
  for (int n_ = 0; n_ < 4; ++n_) blv[n_] = blin[nu*64 + n_*16 + ra];
  float c0a = 0.f, c0b = 0.f, c1a = 0.f, c1b = 0.f;   // c-state for 2 hcols/thread

  f16x8 h0p[16], h1cf[16];          // fragment carries (h0: L1->L0(t+1); h1: Q->L1)
  #pragma unroll
  for (int q_ = 0; q_ < 16; ++q_) { h0p[q_] = f16x8{}; h1cf[q_] = f16x8{}; }
  float nzv[4][4];
  f32x4 acce, acco;

  auto spin = [&](uint32_t* p, uint32_t tgt) {
    if (tid == 0) {
      int g = 0;
      while (__hip_atomic_load(p, __ATOMIC_RELAXED, __HIP_MEMORY_SCOPE_AGENT) < tgt && g < 1000000) {
        __builtin_amdgcn_s_sleep(1); ++g;
      }
    }
    asm volatile("" ::: "memory");
    __syncthreads();
  };
  // fragment load from blocked h: lane needs h[arow][k..k+7]; CALLER passes k = chunk+kg.
  // blocked layout: element (row r, col) at (col>>3)*512 + r*8 + (col&7); k is 8-aligned.
  auto hfrag = [&](const f16* bs, int k) -> f16x8 {
    const f16* p = bs + ((size_t)(k >> 3) * 512 + arow * 8);
    U16B u; u.u[0] = aload64(p); u.u[1] = aload64(p + 4);
    return u.v;
  };
  auto hbase = [&](f16* buf, int par) -> f16* {
    return buf + (size_t)((par*4 + m) * 64) * 512;
  };

  // ---- Q(tq) issue: wait h1(tq) flag, load h1 frags + noise ----
  auto q_issue = [&](int tq) {
    spin(&cntB[(m << 9) + tq], 64u);
    const f16* hb = hbase(h1blk, tq & 1);
    #pragma unroll
    for (int q_ = 0; q_ < 8; ++q_) {
      h1cf[2*q_]     = hfrag(hb, q_*64 + kg);        // R8 FIX: + kg
      h1cf[2*q_ + 1] = hfrag(hb, q_*64 + 32 + kg);   // R8 FIX: + kg
    }
    if (PRE) {
      const float* npp = noise_pre + ((size_t)tq*256 + m*64 + mu*16 + crow)*128 + nu*64 + ra;
      #pragma unroll
      for (int n_ = 0; n_ < 4; ++n_)
        #pragma unroll
        for (int r = 0; r < 4; ++r) nzv[n_][r] = npp[(size_t)r*128 + n_*16];
    }
  };

  // ---- Q(tq) compute: barrier-free GEMM + gumbel softmax -> ctl + out row ----
  auto qblock = [&](int tq) {
    const f16* wq = Wlc + (size_t)(nu*64 + ra) * 512 + kg;
    f32x4 accq[4] = {{0,0,0,0},{0,0,0,0},{0,0,0,0},{0,0,0,0}};
    #pragma unroll
    for (int j = 0; j < 8; ++j) {
      f16x8 ae = h1cf[2*j], ao = h1cf[2*j + 1];
      #pragma unroll
      for (int n_ = 0; n_ < 4; ++n_) {
        f16x8 bE = *(const f16x8*)(wq + (size_t)n_*8192 + j*64);
        f16x8 bO = *(const f16x8*)(wq + (size_t)n_*8192 + j*64 + 32);
        accq[n_] = __builtin_amdgcn_mfma_f32_16x16x32_f16(ae, bE, accq[n_], 0, 0, 0);
        accq[n_] = __builtin_amdgcn_mfma_f32_16x16x32_f16(ao, bO, accq[n_], 0, 0, 0);
      }
    }
    #pragma unroll
    for (int n_ = 0; n_ < 4; ++n_) {
      const int qc = nu*64 + n_*16 + ra;
      #pragma unroll
      for (int r = 0; r < 4; ++r) {
        const int rl = mu*16 + crow + r;
        float g;
        if (PRE) g = nzv[n_][r];
        else {
          const uint32_t nidx = (((uint32_t)tq * 256u + (uint32_t)(m*64 + rl)) * 128u + (uint32_t)qc);
          g = gumbel_noise(nidx);
        }
        float v = (accq[n_][r] + blv[n_] + g) * 10.0f;
        float mx = v;
        #pragma unroll
        for (int k_ = 1; k_ < 16; k_ <<= 1) mx = fmaxf(mx, __shfl_xor(mx, k_));
        float ex = __expf(v - mx);
        float sm = ex;
        #pragma unroll
        for (int k_ = 1; k_ < 16; k_ <<= 1) sm += __shfl_xor(sm, k_);
        float y = ex * __builtin_amdgcn_rcpf(sm);
        ctl[rl][qc] = (f16)y;
      }
    }
    __syncthreads();   // ctl final (cross-wave for L0 partB + out row)
    if (tid < 128)
      out[((size_t)(m*64 + s) * TT + tq) * 128 + tid] = (float)ctl[s][tid];
  };

  // ---- layer epilogue: acc -> glds -> cell (2 hcols/thread) -> coalesced publish+flag ----
  auto epilogue = [&](int L, float& ca, float& cb, f16* blkbuf, int cur, uint32_t* flagp) {
    f32x4 av = acce + acco;
    #pragma unroll
    for (int r = 0; r < 4; ++r)
      glds[mu*16 + crow + r][nu*16 + ra] = av[r];     // C/D: col=lane&15, row=(lane>>4)*4+r
    __syncthreads();
    if (tid < 256) {
      const int h2 = hc2 * 2;
      float ia = glds[erow][h2]      + bls[L][0][h2];
      float ib = glds[erow][h2 + 1]  + bls[L][0][h2 + 1];
      float fa = glds[erow][8 + h2]  + bls[L][1][h2];
      float fb = glds[erow][9 + h2]  + bls[L][1][h2 + 1];
      float ga = glds[erow][16 + h2] + bls[L][2][h2];
      float gb = glds[erow][17 + h2] + bls[L][2][h2 + 1];
      float oa = glds[erow][24 + h2] + bls[L][3][h2];
      float ob = glds[erow][25 + h2] + bls[L][3][h2 + 1];
      float cna = fsig(fa) * ca + fsig(ia) * ftanh(ga);
      float cnb = fsig(fb) * cb + fsig(ib) * ftanh(gb);
      ca = cna; cb = cnb;
      union { f16 h[2]; uint32_t u; } pk;
      pk.h[0] = (f16)(fsig(oa) * ftanh(cna));
      pk.h[1] = (f16)(fsig(ob) * ftanh(cnb));
      uint32_t* pb = (uint32_t*)(blkbuf + (size_t)((cur*4 + m) * 64 + s) * 512);
      astore32(pb + erow*4 + hc2, pk.u);
    }
    asm volatile("s_waitcnt vmcnt(0)" ::: "memory");
    __syncthreads();
    if (tid == 0) flag_add_relaxed(flagp);
  };

  // ==================== main recurrence ====================
  for (int t = 0; t < TT; ++t) {
    const int cur = t & 1;

    // x fragment loads (plain, L2): 16 f32x4 per lane
    const float* xb = states + ((size_t)(m*64 + arow) * TT + t) * 256;
    f32x4 xr[16];
    #pragma unroll
    for (int j = 0; j < 4; ++j) {
      xr[4*j]     = *(const f32x4*)(xb + j*64 + kg);
      xr[4*j + 1] = *(const f32x4*)(xb + j*64 + kg + 4);
      xr[4*j + 2] = *(const f32x4*)(xb + j*64 + 32 + kg);
      xr[4*j + 3] = *(const f32x4*)(xb + j*64 + 32 + kg + 4);
    }

    // Q(t-1) issue: spin + h1 frag loads (latency hides under L0 partA)
    if (t > 0) q_issue(t - 1);

    // ---- L0 partA: chunks 0..3 (x), 4..11 (h0p regs) — barrier-free ----
    acce = f32x4{0,0,0,0}; acco = f32x4{0,0,0,0};
    #pragma unroll
    for (int j = 0; j < 4; ++j) {
      f16x8 ae = cvt8(xr[4*j], xr[4*j + 1]);
      f16x8 ao = cvt8(xr[4*j + 2], xr[4*j + 3]);
      MFMA_PAIR(ae, ao, W0s[nu*16 + ra], j*64)
    }
    #pragma unroll
    for (int j = 4; j < 12; ++j)
      MFMA_PAIR(h0p[2*(j-4)], h0p[2*(j-4) + 1], W0s[nu*16 + ra], j*64)

    // ---- Q(t-1) compute (fills ctl); t=0 keeps one-hot ctl ----
    if (t > 0) qblock(t - 1);

    // ---- L0 partB: ct chunks 12..13 from ctl (LDS frags) ----
    {
      f16x8 ae = *(const f16x8*)&ctl[arow][kg];
      f16x8 ao = *(const f16x8*)&ctl[arow][32 + kg];
      MFMA_PAIR(ae, ao, W0s[nu*16 + ra], 768)
      ae = *(const f16x8*)&ctl[arow][64 + kg];
      ao = *(const f16x8*)&ctl[arow][96 + kg];
      MFMA_PAIR(ae, ao, W0s[nu*16 + ra], 832)
    }
    epilogue(0, c0a, c0b, h0blk, cur, &cntA[(m << 9) + t]);

    // ---- L1 part1: chunks 0..7 (h1cf regs) — barrier-free ----
    acce = f32x4{0,0,0,0}; acco = f32x4{0,0,0,0};
    #pragma unroll
    for (int j = 0; j < 8; ++j)
      MFMA_PAIR(h1cf[2*j], h1cf[2*j + 1], W1s[nu*16 + ra], j*64)

    // ---- h0_cur frags (also next step's h0_prev) ----
    spin(&cntA[(m << 9) + t], 64u);
    {
      const f16* hb0 = hbase(h0blk, cur);
      #pragma unroll
      for (int q_ = 0; q_ < 8; ++q_) {
        h0p[2*q_]     = hfrag(hb0, q_*64 + kg);        // R8 FIX: + kg
        h0p[2*q_ + 1] = hfrag(hb0, q_*64 + 32 + kg);   // R8 FIX: + kg
      }
    }
    // ---- L1 part2: chunks 8..15 (h0 frags) ----
    #pragma unroll
    for (int j = 8; j < 16; ++j)
      MFMA_PAIR(h0p[2*(j-8)], h0p[2*(j-8) + 1], W1s[nu*16 + ra], j*64)

    epilogue(1, c1a, c1b, h1blk, cur, &cntB[(m << 9) + t]);
  }

  // ---- tail: Q for t = TT-1 ----
  q_issue(TT - 1);
  qblock(TT - 1);
}

// ---------------- host ----------------
extern "C" void kernel_launch(void* const* d_in, const int* in_sizes, int n_in,
                              void* d_out, int out_size, void* d_ws, size_t ws_size,
                              hipStream_t stream) {
  const float* states = (const float*)d_in[0];
  const float* Wih0 = (const float*)d_in[1];
  const float* Whh0 = (const float*)d_in[2];
  const float* bih0 = (const float*)d_in[3];
  const float* bhh0 = (const float*)d_in[4];
  const float* Wih1 = (const float*)d_in[5];
  const float* Whh1 = (const float*)d_in[6];
  const float* bih1 = (const float*)d_in[7];
  const float* bhh1 = (const float*)d_in[8];
  const float* Wlin = (const float*)d_in[9];
  const float* blin = (const float*)d_in[10];
  float* out = (float*)d_out;
  (void)in_sizes; (void)n_in; (void)out_size;

  char* ws = (char*)d_ws;
  uint32_t* cntA = (uint32_t*)ws;                       // [4][512] = 8192 B
  uint32_t* cntB = (uint32_t*)(ws + 8192);              // 8192 B
  uint32_t* cnt0 = (uint32_t*)(ws + 16384);             // 4 B (pad to 256)
  const size_t cnt_bytes = 16640;
  f16* h0blk = (f16*)(ws + cnt_bytes);                  // 524,288 B (blocked layout)
  f16* h1blk = (f16*)(ws + cnt_bytes + 524288);         // 524,288 B
  f16* Wlc   = (f16*)(ws + cnt_bytes + 2 * 524288);     // 131,072 B
  float* noise = (float*)(ws + cnt_bytes + 2 * 524288 + 131072);  // 67,108,864 B
  const size_t need = cnt_bytes + 2 * 524288 + 131072 + 67108864;

  hipMemsetAsync(ws, 0, cnt_bytes, stream);
  if (ws_size >= need) {
    persistent_kernel<true><<<256, 512, 0, stream>>>(
        states, Wih0, Whh0, bih0, bhh0, Wih1, Whh1, bih1, bhh1, Wlin, blin,
        out, cnt0, cntA, cntB, h0blk, h1blk, Wlc, noise);
  } else {
    persistent_kernel<false><<<256, 512, 0, stream>>>(
        states, Wih0, Whh0, bih0, bhh0, Wih1, Whh1, bih1, bhh1, Wlin, blin,
        out, cnt0, cntA, cntB, h0blk, h1blk, Wlc, nullptr);
  }
}

// Round 9
// 19285.313 us; speedup vs baseline: 1.0819x; 1.0819x over previous
//
#include <hip/hip_runtime.h>
#include <cstdint>
#include <cstddef>

// Problem constants
#define BB 256     // batch
#define TT 512     // time steps
#define HH 512     // hidden
// 256 blocks = 4 m-groups (64 rows) x 64 s-slices (8 hcols = 32 gatecols/layer), 512 thr.
// R9 = R8 structure (barrier-free fragment-direct GEMMs, 7 barriers/step) with ONE change:
// h exchange uses TIME-INDEXED slabs ([t][m] blocked layout, never address-reused within a
// launch) so consumer fragment reads are PLAIN CACHEABLE loads (L2 absorbs the 64-block
// per-m-group read redundancy; R8's relaxed-atomic reads bypassed L2 -> 14 GB FETCH).
// Producers still publish via relaxed-atomic write-through stores + vmcnt(0) + flag, so a
// consumer's first-ever (cold) read of a line is ordered after the data reached the LLC.
// Across graph replays the kernel-dispatch acquire invalidates L2 (no stale lines).
// MODE2: hist h + noise table; MODE1: hist h, on-fly noise; MODE0: exact-R8 fallback.

typedef _Float16 f16;
typedef _Float16 f16x8 __attribute__((ext_vector_type(8)));
typedef float f32x4 __attribute__((ext_vector_type(4)));

union U16B { uint64_t u[2]; f16x8 v; };

// ---------------- threefry2x32 (key = (0,42)), jax_threefry_partitionable ----------------
__device__ __forceinline__ void tf_round(uint32_t& x0, uint32_t& x1, const int r) {
  x0 += x1;
  x1 = (x1 << r) | (x1 >> (32 - r));
  x1 ^= x0;
}

__device__ __forceinline__ void threefry2x32(uint32_t c0, uint32_t c1, uint32_t& o0, uint32_t& o1) {
  const uint32_t ks0 = 0u, ks1 = 42u;
  const uint32_t ks2 = 0x1BD11BDAu ^ ks0 ^ ks1;
  uint32_t x0 = c0 + ks0, x1 = c1 + ks1;
  tf_round(x0,x1,13); tf_round(x0,x1,15); tf_round(x0,x1,26); tf_round(x0,x1,6);
  x0 += ks1; x1 += ks2 + 1u;
  tf_round(x0,x1,17); tf_round(x0,x1,29); tf_round(x0,x1,16); tf_round(x0,x1,24);
  x0 += ks2; x1 += ks0 + 2u;
  tf_round(x0,x1,13); tf_round(x0,x1,15); tf_round(x0,x1,26); tf_round(x0,x1,6);
  x0 += ks0; x1 += ks1 + 3u;
  tf_round(x0,x1,17); tf_round(x0,x1,29); tf_round(x0,x1,16); tf_round(x0,x1,24);
  x0 += ks1; x1 += ks2 + 4u;
  tf_round(x0,x1,13); tf_round(x0,x1,15); tf_round(x0,x1,26); tf_round(x0,x1,6);
  x0 += ks2; x1 += ks0 + 5u;
  o0 = x0; o1 = x1;
}

__device__ __forceinline__ float gumbel_noise(uint32_t idx, bool fast) {
  uint32_t o0, o1;
  threefry2x32(0u, idx, o0, o1);
  uint32_t bits = o0 ^ o1;
  uint32_t fb = (bits >> 9) | 0x3f800000u;
  float u = __uint_as_float(fb) - 1.0f;
  const float tiny = 1.17549435e-38f;
  u = fmaxf(tiny, u + tiny);
  if (fast) return -__logf(-__logf(u));
  return -logf(-logf(u));
}

// ---------------- fast transcendentals (err ~1e-6, tolerance 2e-2) ----------------
__device__ __forceinline__ float fsig(float x) {
  return __builtin_amdgcn_rcpf(1.0f + __expf(-x));
}
__device__ __forceinline__ float ftanh(float x) {
  float xx = fminf(fmaxf(x, -15.f), 15.f);
  float t = __expf(2.f * xx);
  return (t - 1.f) * __builtin_amdgcn_rcpf(t + 1.f);
}

// ---------------- atomics (relaxed agent = write-through to coherence point) ----------------
__device__ __forceinline__ uint64_t aload64(const f16* p) {
  return __hip_atomic_load((const uint64_t*)p, __ATOMIC_RELAXED, __HIP_MEMORY_SCOPE_AGENT);
}
__device__ __forceinline__ void astore32(uint32_t* p, uint32_t v) {
  __hip_atomic_store(p, v, __ATOMIC_RELAXED, __HIP_MEMORY_SCOPE_AGENT);
}
__device__ __forceinline__ void flag_add_relaxed(uint32_t* p) {
  __hip_atomic_fetch_add(p, 1u, __ATOMIC_RELAXED, __HIP_MEMORY_SCOPE_AGENT);
}

__device__ __forceinline__ f16x8 cvt8(f32x4 a, f32x4 b) {
  f16x8 w;
  w[0]=(f16)a[0]; w[1]=(f16)a[1]; w[2]=(f16)a[2]; w[3]=(f16)a[3];
  w[4]=(f16)b[0]; w[5]=(f16)b[1]; w[6]=(f16)b[2]; w[7]=(f16)b[3];
  return w;
}

// MFMA pair on a 64-k chunk: AE covers k..k+31, AO k+32..k+63 (per-lane 8 f16 each)
#define MFMA_PAIR(AE, AO, WROW, KOFF) { \
  f16x8 be_ = *(const f16x8*)&(WROW)[(KOFF) + kg]; \
  f16x8 bo_ = *(const f16x8*)&(WROW)[(KOFF) + 32 + kg]; \
  acce = __builtin_amdgcn_mfma_f32_16x16x32_f16((AE), be_, acce, 0, 0, 0); \
  acco = __builtin_amdgcn_mfma_f32_16x16x32_f16((AO), bo_, acco, 0, 0, 0); }

// ---------------- the persistent kernel ----------------
// MODE: 2 = t-indexed h slabs + noise table; 1 = t-indexed h, on-fly noise; 0 = R8 fallback
template<int MODE>
__global__ __launch_bounds__(512, 1) void persistent_kernel(
    const float* __restrict__ states,
    const float* __restrict__ Wih0, const float* __restrict__ Whh0,
    const float* __restrict__ bih0, const float* __restrict__ bhh0,
    const float* __restrict__ Wih1, const float* __restrict__ Whh1,
    const float* __restrict__ bih1, const float* __restrict__ bhh1,
    const float* __restrict__ Wlin, const float* __restrict__ blin,
    float* __restrict__ out,
    uint32_t* cnt0, uint32_t* cntA, uint32_t* cntB,
    f16* h0blk, f16* h1blk, f16* Wlc, float* noise_pre)
{
  __shared__ __align__(16) f16 W0s[32][904];    // 57,856 B
  __shared__ __align__(16) f16 W1s[32][1032];   // 66,048 B
  __shared__ __align__(16) f16 ctl[64][136];    // 17,408 B
  __shared__ float glds[64][37];                //  9,472 B
  __shared__ float bls[2][4][8];                //    256 B   (total ~151 KB)

  const int tid = threadIdx.x;
  const int bid = blockIdx.x;
  const int m = bid & 3;            // m-group (64 batch rows)
  const int s = bid >> 2;           // h-col slice 0..63 (8 cols)
  const int lane = tid & 63;
  const int wv = tid >> 6;
  const int mu = wv >> 1;           // 16-row tile 0..3
  const int nu = wv & 1;            // 16-gatecol tile (Q: 64-col tile)
  const int ra = lane & 15;
  const int kg = (lane >> 4) << 3;
  const int crow = (lane >> 4) << 2;
  const int arow = mu * 16 + ra;    // this lane's A-fragment row (local 0..63)
  const int erow = tid >> 2;        // cell row (tid<256)
  const int hc2 = tid & 3;          // cell hcol pair index

  // ---- one-time LDS W init (f32 -> f16, reordered K) ----
  {
    const int lc = tid & 31;
    const int gr = ((lc >> 3) << 9) + s*8 + (lc & 7);   // gate*512 + hcol
    for (int k = tid >> 5; k < 896; k += 16) {
      float v;
      if (k < 256)      v = Wih0[(size_t)gr * 384 + k];              // x
      else if (k < 768) v = Whh0[(size_t)gr * 512 + (k - 256)];      // h0_prev
      else              v = Wih0[(size_t)gr * 384 + 256 + (k - 768)];// ct
      W0s[lc][k] = (f16)v;
    }
    for (int k = tid >> 5; k < 1024; k += 16) {
      float v = (k < 512) ? Whh1[(size_t)gr * 512 + k]               // h1_prev
                          : Wih1[(size_t)gr * 512 + (k - 512)];      // h0_cur
      W1s[lc][k] = (f16)v;
    }
  }
  for (int e = tid; e < 64 * 128; e += 512)
    ctl[e >> 7][e & 127] = (f16)(((e & 15) == 0) ? 1.f : 0.f);
  if (tid < 64) {                    // biases -> LDS: bls[layer][gate][hc]
    const int l = tid >> 5, g = (tid >> 3) & 3, hc = tid & 7;
    const int col = g * 512 + s*8 + hc;
    bls[l][g][hc] = l ? (bih1[col] + bhh1[col]) : (bih0[col] + bhh0[col]);
  }

  // ---- global init: Wlc + noise (plain stores; flushed by the startup RELEASE) ----
  if (tid < 128) {
    const int e2 = bid * 128 + tid;
    union { f16 h[2]; uint32_t u; } pk2;
    pk2.h[0] = (f16)Wlin[2*e2]; pk2.h[1] = (f16)Wlin[2*e2 + 1];
    ((uint32_t*)Wlc)[e2] = pk2.u;
  }
  if (MODE != 1) {
    const uint32_t base = (uint32_t)bid * 65536u;
    for (uint32_t e = tid; e < 65536u; e += 512u)
      noise_pre[base + e] = gumbel_noise(base + e, false);
  }
  // ---- startup barrier: the ONLY cache-maintaining release/acquire ----
  __syncthreads();
  if (tid == 0) {
    __hip_atomic_fetch_add(cnt0, 1u, __ATOMIC_RELEASE, __HIP_MEMORY_SCOPE_AGENT);
    int g = 0;
    while (__hip_atomic_load(cnt0, __ATOMIC_RELAXED, __HIP_MEMORY_SCOPE_AGENT) < 256u && g < 2000000) {
      __builtin_amdgcn_s_sleep(1); ++g;
    }
    (void)__hip_atomic_load(cnt0, __ATOMIC_ACQUIRE, __HIP_MEMORY_SCOPE_AGENT);
  }
  __syncthreads();

  // ---- per-thread constants / state ----
  float blv[4];
  #pragma unroll
  for (int n_ = 0; n_ < 4; ++n_) blv[n_] = blin[nu*64 + n_*16 + ra];
  float c0a = 0.f, c0b = 0.f, c1a = 0.f, c1b = 0.f;   // c-state for 2 hcols/thread

  f16x8 h0p[16], h1cf[16];          // fragment carries (h0: L1->L0(t+1); h1: Q->L1)
  #pragma unroll
  for (int q_ = 0; q_ < 16; ++q_) { h0p[q_] = f16x8{}; h1cf[q_] = f16x8{}; }
  float nzv[4][4];
  f32x4 acce, acco;

  auto spin = [&](uint32_t* p, uint32_t tgt) {
    if (tid == 0) {
      int g = 0;
      while (__hip_atomic_load(p, __ATOMIC_RELAXED, __HIP_MEMORY_SCOPE_AGENT) < tgt && g < 1000000) {
        __builtin_amdgcn_s_sleep(1); ++g;
      }
    }
    asm volatile("" ::: "memory");
    __syncthreads();
  };
  // slab base: MODE>=1 -> per-timestep slab (cold lines, cacheable); MODE0 -> parity
  auto hbase = [&](f16* buf, int t) -> f16* {
    const size_t slab = (size_t)((MODE ? t : (t & 1)) * 4 + m) * 32768;
    return buf + slab;
  };
  // fragment read: lane needs h[arow][k..k+7]; k = chunk + kg (8-aligned).
  // blocked layout: (row r, col c) at (c>>3)*512 + r*8 + (c&7)
  auto hfrag = [&](const f16* bs, int k) -> f16x8 {
    const f16* p = bs + ((size_t)(k >> 3) * 512 + arow * 8);
    if (MODE >= 1) {
      return *(const f16x8*)p;                        // plain cacheable (cold line)
    } else {
      U16B u; u.u[0] = aload64(p); u.u[1] = aload64(p + 4);
      return u.v;
    }
  };

  // ---- Q(tq) issue: wait h1(tq) flag, load h1 frags + noise ----
  auto q_issue = [&](int tq) {
    spin(&cntB[(m << 9) + tq], 64u);
    const f16* hb = hbase(h1blk, tq);
    #pragma unroll
    for (int q_ = 0; q_ < 8; ++q_) {
      h1cf[2*q_]     = hfrag(hb, q_*64 + kg);
      h1cf[2*q_ + 1] = hfrag(hb, q_*64 + 32 + kg);
    }
    if (MODE != 1) {
      const float* npp = noise_pre + ((size_t)tq*256 + m*64 + mu*16 + crow)*128 + nu*64 + ra;
      #pragma unroll
      for (int n_ = 0; n_ < 4; ++n_)
        #pragma unroll
        for (int r = 0; r < 4; ++r) nzv[n_][r] = npp[(size_t)r*128 + n_*16];
    }
  };

  // ---- Q(tq) compute: barrier-free GEMM + gumbel softmax -> ctl + out row ----
  auto qblock = [&](int tq) {
    const f16* wq = Wlc + (size_t)(nu*64 + ra) * 512 + kg;
    f32x4 accq[4] = {{0,0,0,0},{0,0,0,0},{0,0,0,0},{0,0,0,0}};
    #pragma unroll
    for (int j = 0; j < 8; ++j) {
      f16x8 ae = h1cf[2*j], ao = h1cf[2*j + 1];
      #pragma unroll
      for (int n_ = 0; n_ < 4; ++n_) {
        f16x8 bE = *(const f16x8*)(wq + (size_t)n_*8192 + j*64);
        f16x8 bO = *(const f16x8*)(wq + (size_t)n_*8192 + j*64 + 32);
        accq[n_] = __builtin_amdgcn_mfma_f32_16x16x32_f16(ae, bE, accq[n_], 0, 0, 0);
        accq[n_] = __builtin_amdgcn_mfma_f32_16x16x32_f16(ao, bO, accq[n_], 0, 0, 0);
      }
    }
    #pragma unroll
    for (int n_ = 0; n_ < 4; ++n_) {
      const int qc = nu*64 + n_*16 + ra;
      #pragma unroll
      for (int r = 0; r < 4; ++r) {
        const int rl = mu*16 + crow + r;
        float g;
        if (MODE != 1) g = nzv[n_][r];
        else {
          const uint32_t nidx = (((uint32_t)tq * 256u + (uint32_t)(m*64 + rl)) * 128u + (uint32_t)qc);
          g = gumbel_noise(nidx, true);
        }
        float v = (accq[n_][r] + blv[n_] + g) * 10.0f;
        float mx = v;
        #pragma unroll
        for (int k_ = 1; k_ < 16; k_ <<= 1) mx = fmaxf(mx, __shfl_xor(mx, k_));
        float ex = __expf(v - mx);
        float sm = ex;
        #pragma unroll
        for (int k_ = 1; k_ < 16; k_ <<= 1) sm += __shfl_xor(sm, k_);
        float y = ex * __builtin_amdgcn_rcpf(sm);
        ctl[rl][qc] = (f16)y;
      }
    }
    __syncthreads();   // ctl final (cross-wave for L0 partB + out row)
    if (tid < 128)
      out[((size_t)(m*64 + s) * TT + tq) * 128 + tid] = (float)ctl[s][tid];
  };

  // ---- layer epilogue: acc -> glds -> cell (2 hcols/thread) -> coalesced publish+flag ----
  auto epilogue = [&](int L, float& ca, float& cb, f16* blkbuf, int t, uint32_t* flagp) {
    f32x4 av = acce + acco;
    #pragma unroll
    for (int r = 0; r < 4; ++r)
      glds[mu*16 + crow + r][nu*16 + ra] = av[r];     // C/D: col=lane&15, row=(lane>>4)*4+r
    __syncthreads();
    if (tid < 256) {
      const int h2 = hc2 * 2;
      float ia = glds[erow][h2]      + bls[L][0][h2];
      float ib = glds[erow][h2 + 1]  + bls[L][0][h2 + 1];
      float fa = glds[erow][8 + h2]  + bls[L][1][h2];
      float fb = glds[erow][9 + h2]  + bls[L][1][h2 + 1];
      float ga = glds[erow][16 + h2] + bls[L][2][h2];
      float gb = glds[erow][17 + h2] + bls[L][2][h2 + 1];
      float oa = glds[erow][24 + h2] + bls[L][3][h2];
      float ob = glds[erow][25 + h2] + bls[L][3][h2 + 1];
      float cna = fsig(fa) * ca + fsig(ia) * ftanh(ga);
      float cnb = fsig(fb) * cb + fsig(ib) * ftanh(gb);
      ca = cna; cb = cnb;
      union { f16 h[2]; uint32_t u; } pk;
      pk.h[0] = (f16)(fsig(oa) * ftanh(cna));
      pk.h[1] = (f16)(fsig(ob) * ftanh(cnb));
      uint32_t* pb = (uint32_t*)(hbase(blkbuf, t) + (size_t)s * 512);
      astore32(pb + erow*4 + hc2, pk.u);              // write-through publish (1 KB/block)
    }
    asm volatile("s_waitcnt vmcnt(0)" ::: "memory");
    __syncthreads();
    if (tid == 0) flag_add_relaxed(flagp);
  };

  // ==================== main recurrence ====================
  for (int t = 0; t < TT; ++t) {
    // x fragment loads (plain, L2): 16 f32x4 per lane
    const float* xb = states + ((size_t)(m*64 + arow) * TT + t) * 256;
    f32x4 xr[16];
    #pragma unroll
    for (int j = 0; j < 4; ++j) {
      xr[4*j]     = *(const f32x4*)(xb + j*64 + kg);
      xr[4*j + 1] = *(const f32x4*)(xb + j*64 + kg + 4);
      xr[4*j + 2] = *(const f32x4*)(xb + j*64 + 32 + kg);
      xr[4*j + 3] = *(const f32x4*)(xb + j*64 + 32 + kg + 4);
    }

    // Q(t-1) issue: spin + h1 frag loads (latency hides under L0 partA)
    if (t > 0) q_issue(t - 1);

    // ---- L0 partA: chunks 0..3 (x), 4..11 (h0p regs) — barrier-free ----
    acce = f32x4{0,0,0,0}; acco = f32x4{0,0,0,0};
    #pragma unroll
    for (int j = 0; j < 4; ++j) {
      f16x8 ae = cvt8(xr[4*j], xr[4*j + 1]);
      f16x8 ao = cvt8(xr[4*j + 2], xr[4*j + 3]);
      MFMA_PAIR(ae, ao, W0s[nu*16 + ra], j*64)
    }
    #pragma unroll
    for (int j = 4; j < 12; ++j)
      MFMA_PAIR(h0p[2*(j-4)], h0p[2*(j-4) + 1], W0s[nu*16 + ra], j*64)

    // ---- Q(t-1) compute (fills ctl); t=0 keeps one-hot ctl ----
    if (t > 0) qblock(t - 1);

    // ---- L0 partB: ct chunks 12..13 from ctl (LDS frags) ----
    {
      f16x8 ae = *(const f16x8*)&ctl[arow][kg];
      f16x8 ao = *(const f16x8*)&ctl[arow][32 + kg];
      MFMA_PAIR(ae, ao, W0s[nu*16 + ra], 768)
      ae = *(const f16x8*)&ctl[arow][64 + kg];
      ao = *(const f16x8*)&ctl[arow][96 + kg];
      MFMA_PAIR(ae, ao, W0s[nu*16 + ra], 832)
    }
    epilogue(0, c0a, c0b, h0blk, t, &cntA[(m << 9) + t]);

    // ---- L1 part1: chunks 0..7 (h1cf regs) — barrier-free ----
    acce = f32x4{0,0,0,0}; acco = f32x4{0,0,0,0};
    #pragma unroll
    for (int j = 0; j < 8; ++j)
      MFMA_PAIR(h1cf[2*j], h1cf[2*j + 1], W1s[nu*16 + ra], j*64)

    // ---- h0_cur frags (also next step's h0_prev) ----
    spin(&cntA[(m << 9) + t], 64u);
    {
      const f16* hb0 = hbase(h0blk, t);
      #pragma unroll
      for (int q_ = 0; q_ < 8; ++q_) {
        h0p[2*q_]     = hfrag(hb0, q_*64 + kg);
        h0p[2*q_ + 1] = hfrag(hb0, q_*64 + 32 + kg);
      }
    }
    // ---- L1 part2: chunks 8..15 (h0 frags) ----
    #pragma unroll
    for (int j = 8; j < 16; ++j)
      MFMA_PAIR(h0p[2*(j-8)], h0p[2*(j-8) + 1], W1s[nu*16 + ra], j*64)

    epilogue(1, c1a, c1b, h1blk, t, &cntB[(m << 9) + t]);
  }

  // ---- tail: Q for t = TT-1 ----
  q_issue(TT - 1);
  qblock(TT - 1);
}

// ---------------- host ----------------
extern "C" void kernel_launch(void* const* d_in, const int* in_sizes, int n_in,
                              void* d_out, int out_size, void* d_ws, size_t ws_size,
                              hipStream_t stream) {
  const float* states = (const float*)d_in[0];
  const float* Wih0 = (const float*)d_in[1];
  const float* Whh0 = (const float*)d_in[2];
  const float* bih0 = (const float*)d_in[3];
  const float* bhh0 = (const float*)d_in[4];
  const float* Wih1 = (const float*)d_in[5];
  const float* Whh1 = (const float*)d_in[6];
  const float* bih1 = (const float*)d_in[7];
  const float* bhh1 = (const float*)d_in[8];
  const float* Wlin = (const float*)d_in[9];
  const float* blin = (const float*)d_in[10];
  float* out = (float*)d_out;
  (void)in_sizes; (void)n_in; (void)out_size;

  char* ws = (char*)d_ws;
  uint32_t* cntA = (uint32_t*)ws;                       // [4][512] = 8192 B
  uint32_t* cntB = (uint32_t*)(ws + 8192);              // 8192 B
  uint32_t* cnt0 = (uint32_t*)(ws + 16384);             // 4 B (pad to 256)
  const size_t cnt_bytes = 16640;
  f16* Wlc = (f16*)(ws + cnt_bytes);                    // 131,072 B
  char* p = ws + cnt_bytes + 131072;

  const size_t hist_bytes  = (size_t)TT * 4 * 32768 * 2;   // 134,217,728 per layer
  const size_t par_bytes   = (size_t)2  * 4 * 32768 * 2;   // 524,288 per layer
  const size_t noise_bytes = 67108864;

  const size_t need2 = cnt_bytes + 131072 + 2*hist_bytes + noise_bytes; // ~336 MB
  const size_t need1 = cnt_bytes + 131072 + 2*hist_bytes;               // ~269 MB
  hipMemsetAsync(ws, 0, cnt_bytes, stream);

  if (ws_size >= need2) {
    f16* h0b = (f16*)p;
    f16* h1b = (f16*)(p + hist_bytes);
    float* noise = (float*)(p + 2*hist_bytes);
    persistent_kernel<2><<<256, 512, 0, stream>>>(
        states, Wih0, Whh0, bih0, bhh0, Wih1, Whh1, bih1, bhh1, Wlin, blin,
        out, cnt0, cntA, cntB, h0b, h1b, Wlc, noise);
  } else if (ws_size >= need1) {
    f16* h0b = (f16*)p;
    f16* h1b = (f16*)(p + hist_bytes);
    persistent_kernel<1><<<256, 512, 0, stream>>>(
        states, Wih0, Whh0, bih0, bhh0, Wih1, Whh1, bih1, bhh1, Wlin, blin,
        out, cnt0, cntA, cntB, h0b, h1b, Wlc, nullptr);
  } else {
    f16* h0b = (f16*)p;
    f16* h1b = (f16*)(p + par_bytes);
    float* noise = (float*)(p + 2*par_bytes);
    persistent_kernel<0><<<256, 512, 0, stream>>>(
        states, Wih0, Whh0, bih0, bhh0, Wih1, Whh1, bih1, bhh1, Wlin, blin,
        out, cnt0, cntA, cntB, h0b, h1b, Wlc, noise);
  }
}

// Round 10
// 16970.172 us; speedup vs baseline: 1.2295x; 1.1364x over previous
//
#include <hip/hip_runtime.h>
#include <cstdint>
#include <cstddef>

// Problem constants
#define BB 256     // batch
#define TT 512     // time steps
#define HH 512     // hidden
// 256 blocks = 4 m-groups (64 rows) x 64 s-slices (8 hcols = 32 gatecols/layer), 512 thr.
// R10 = R9 (barrier-free fragment-direct GEMMs, t-indexed h slabs, plain cacheable reads)
// + (1) PARALLEL flag vectors: per-step flags[t][m][64]; producer = ONE atomic store per
//   block (no 64-way RMW serialization at the LLC); waiter = wave0 64-lane atomic gather
//   + __ballot poll.  + (2) x preconverted at startup to f16 FRAGMENT-layout t-major
//   slabs (halved bytes, sequential slabs, zero per-step cvt VALU).
// M=2: xf16+noise table; M=1: noise table only (x from f32 as R9); M=0: neither.

typedef _Float16 f16;
typedef _Float16 f16x8 __attribute__((ext_vector_type(8)));
typedef float f32x4 __attribute__((ext_vector_type(4)));

union U16B { uint64_t u[2]; f16x8 v; };

// ---------------- threefry2x32 (key = (0,42)), jax_threefry_partitionable ----------------
__device__ __forceinline__ void tf_round(uint32_t& x0, uint32_t& x1, const int r) {
  x0 += x1;
  x1 = (x1 << r) | (x1 >> (32 - r));
  x1 ^= x0;
}

__device__ __forceinline__ void threefry2x32(uint32_t c0, uint32_t c1, uint32_t& o0, uint32_t& o1) {
  const uint32_t ks0 = 0u, ks1 = 42u;
  const uint32_t ks2 = 0x1BD11BDAu ^ ks0 ^ ks1;
  uint32_t x0 = c0 + ks0, x1 = c1 + ks1;
  tf_round(x0,x1,13); tf_round(x0,x1,15); tf_round(x0,x1,26); tf_round(x0,x1,6);
  x0 += ks1; x1 += ks2 + 1u;
  tf_round(x0,x1,17); tf_round(x0,x1,29); tf_round(x0,x1,16); tf_round(x0,x1,24);
  x0 += ks2; x1 += ks0 + 2u;
  tf_round(x0,x1,13); tf_round(x0,x1,15); tf_round(x0,x1,26); tf_round(x0,x1,6);
  x0 += ks0; x1 += ks1 + 3u;
  tf_round(x0,x1,17); tf_round(x0,x1,29); tf_round(x0,x1,16); tf_round(x0,x1,24);
  x0 += ks1; x1 += ks2 + 4u;
  tf_round(x0,x1,13); tf_round(x0,x1,15); tf_round(x0,x1,26); tf_round(x0,x1,6);
  x0 += ks2; x1 += ks0 + 5u;
  o0 = x0; o1 = x1;
}

__device__ __forceinline__ float gumbel_noise(uint32_t idx, bool fast) {
  uint32_t o0, o1;
  threefry2x32(0u, idx, o0, o1);
  uint32_t bits = o0 ^ o1;
  uint32_t fb = (bits >> 9) | 0x3f800000u;
  float u = __uint_as_float(fb) - 1.0f;
  const float tiny = 1.17549435e-38f;
  u = fmaxf(tiny, u + tiny);
  if (fast) return -__logf(-__logf(u));
  return -logf(-logf(u));
}

// ---------------- fast transcendentals (err ~1e-6, tolerance 2e-2) ----------------
__device__ __forceinline__ float fsig(float x) {
  return __builtin_amdgcn_rcpf(1.0f + __expf(-x));
}
__device__ __forceinline__ float ftanh(float x) {
  float xx = fminf(fmaxf(x, -15.f), 15.f);
  float t = __expf(2.f * xx);
  return (t - 1.f) * __builtin_amdgcn_rcpf(t + 1.f);
}

// ---------------- atomics (relaxed agent = write-through/bypass to coherence point) -------
__device__ __forceinline__ uint32_t aload32(const uint32_t* p) {
  return __hip_atomic_load(p, __ATOMIC_RELAXED, __HIP_MEMORY_SCOPE_AGENT);
}
__device__ __forceinline__ void astore32(uint32_t* p, uint32_t v) {
  __hip_atomic_store(p, v, __ATOMIC_RELAXED, __HIP_MEMORY_SCOPE_AGENT);
}

__device__ __forceinline__ f16x8 cvt8(f32x4 a, f32x4 b) {
  f16x8 w;
  w[0]=(f16)a[0]; w[1]=(f16)a[1]; w[2]=(f16)a[2]; w[3]=(f16)a[3];
  w[4]=(f16)b[0]; w[5]=(f16)b[1]; w[6]=(f16)b[2]; w[7]=(f16)b[3];
  return w;
}

// MFMA pair on a 64-k chunk: AE covers k..k+31, AO k+32..k+63 (per-lane 8 f16 each)
#define MFMA_PAIR(AE, AO, WROW, KOFF) { \
  f16x8 be_ = *(const f16x8*)&(WROW)[(KOFF) + kg]; \
  f16x8 bo_ = *(const f16x8*)&(WROW)[(KOFF) + 32 + kg]; \
  acce = __builtin_amdgcn_mfma_f32_16x16x32_f16((AE), be_, acce, 0, 0, 0); \
  acco = __builtin_amdgcn_mfma_f32_16x16x32_f16((AO), bo_, acco, 0, 0, 0); }

// ---------------- the persistent kernel ----------------
template<int M>
__global__ __launch_bounds__(512, 1) void persistent_kernel(
    const float* __restrict__ states,
    const float* __restrict__ Wih0, const float* __restrict__ Whh0,
    const float* __restrict__ bih0, const float* __restrict__ bhh0,
    const float* __restrict__ Wih1, const float* __restrict__ Whh1,
    const float* __restrict__ bih1, const float* __restrict__ bhh1,
    const float* __restrict__ Wlin, const float* __restrict__ blin,
    float* __restrict__ out,
    uint32_t* cnt0, uint32_t* flagsA, uint32_t* flagsB,
    f16* h0blk, f16* h1blk, f16* Wlc, float* noise_pre, f16* xf16)
{
  __shared__ __align__(16) f16 W0s[32][904];    // 57,856 B
  __shared__ __align__(16) f16 W1s[32][1032];   // 66,048 B
  __shared__ __align__(16) f16 ctl[64][136];    // 17,408 B
  __shared__ float glds[64][37];                //  9,472 B
  __shared__ float bls[2][4][8];                //    256 B   (total ~151 KB)

  const int tid = threadIdx.x;
  const int bid = blockIdx.x;
  const int m = bid & 3;            // m-group (64 batch rows)
  const int s = bid >> 2;           // h-col slice 0..63 (8 cols)
  const int lane = tid & 63;
  const int wv = tid >> 6;
  const int mu = wv >> 1;           // 16-row tile 0..3
  const int nu = wv & 1;            // 16-gatecol tile (Q: 64-col tile)
  const int ra = lane & 15;
  const int kg = (lane >> 4) << 3;
  const int crow = (lane >> 4) << 2;
  const int arow = mu * 16 + ra;    // this lane's A-fragment row (local 0..63)
  const int erow = tid >> 2;        // cell row (tid<256)
  const int hc2 = tid & 3;          // cell hcol pair index

  // ---- one-time LDS W init (f32 -> f16, reordered K) ----
  {
    const int lc = tid & 31;
    const int gr = ((lc >> 3) << 9) + s*8 + (lc & 7);   // gate*512 + hcol
    for (int k = tid >> 5; k < 896; k += 16) {
      float v;
      if (k < 256)      v = Wih0[(size_t)gr * 384 + k];              // x
      else if (k < 768) v = Whh0[(size_t)gr * 512 + (k - 256)];      // h0_prev
      else              v = Wih0[(size_t)gr * 384 + 256 + (k - 768)];// ct
      W0s[lc][k] = (f16)v;
    }
    for (int k = tid >> 5; k < 1024; k += 16) {
      float v = (k < 512) ? Whh1[(size_t)gr * 512 + k]               // h1_prev
                          : Wih1[(size_t)gr * 512 + (k - 512)];      // h0_cur
      W1s[lc][k] = (f16)v;
    }
  }
  for (int e = tid; e < 64 * 128; e += 512)
    ctl[e >> 7][e & 127] = (f16)(((e & 15) == 0) ? 1.f : 0.f);
  if (tid < 64) {                    // biases -> LDS: bls[layer][gate][hc]
    const int l = tid >> 5, g = (tid >> 3) & 3, hc = tid & 7;
    const int col = g * 512 + s*8 + hc;
    bls[l][g][hc] = l ? (bih1[col] + bhh1[col]) : (bih0[col] + bhh0[col]);
  }

  // ---- global init (plain stores; flushed by startup RELEASE) ----
  if (tid < 128) {
    const int e2 = bid * 128 + tid;
    union { f16 h[2]; uint32_t u; } pk2;
    pk2.h[0] = (f16)Wlin[2*e2]; pk2.h[1] = (f16)Wlin[2*e2 + 1];
    ((uint32_t*)Wlc)[e2] = pk2.u;
  }
  if (M >= 1) {                      // noise table: 65536 floats per block
    const uint32_t base = (uint32_t)bid * 65536u;
    for (uint32_t e = tid; e < 65536u; e += 512u)
      noise_pre[base + e] = gumbel_noise(base + e, false);
  }
  if (M >= 2) {                      // x -> f16 fragment-layout slabs [t][m][16384]
    #pragma unroll
    for (int tt2 = 0; tt2 < 2; ++tt2) {
      const int tx = bid * 2 + tt2;
      const int r = tid >> 3;                   // 0..63
      const int kb = (tid & 7) * 32;            // 0..224
      #pragma unroll
      for (int mm = 0; mm < 4; ++mm) {
        const float* src = states + ((size_t)(mm*64 + r) * TT + tx) * 256 + kb;
        f16* dst = xf16 + ((size_t)tx*4 + mm) * 16384;
        #pragma unroll
        for (int j = 0; j < 4; ++j) {
          f32x4 a = *(const f32x4*)(src + j*8);
          f32x4 b = *(const f32x4*)(src + j*8 + 4);
          f16x8 w = cvt8(a, b);
          *(f16x8*)(dst + (size_t)((kb + j*8) >> 3) * 512 + r*8) = w;
        }
      }
    }
  }
  // ---- startup barrier: the ONLY cache-maintaining release/acquire ----
  __syncthreads();
  if (tid == 0) {
    __hip_atomic_fetch_add(cnt0, 1u, __ATOMIC_RELEASE, __HIP_MEMORY_SCOPE_AGENT);
    int g = 0;
    while (aload32(cnt0) < 256u && g < 2000000) { __builtin_amdgcn_s_sleep(1); ++g; }
    (void)__hip_atomic_load(cnt0, __ATOMIC_ACQUIRE, __HIP_MEMORY_SCOPE_AGENT);
  }
  __syncthreads();

  // ---- per-thread constants / state ----
  float blv[4];
  #pragma unroll
  for (int n_ = 0; n_ < 4; ++n_) blv[n_] = blin[nu*64 + n_*16 + ra];
  float c0a = 0.f, c0b = 0.f, c1a = 0.f, c1b = 0.f;   // c-state for 2 hcols/thread

  f16x8 h0p[16], h1cf[16];          // fragment carries (h0: L1->L0(t+1); h1: Q->L1)
  #pragma unroll
  for (int q_ = 0; q_ < 16; ++q_) { h0p[q_] = f16x8{}; h1cf[q_] = f16x8{}; }
  float nzv[4][4];
  f32x4 acce, acco;

  // ---- parallel flag-vector wait: wave0 gathers 64 flags, ballots until all set ----
  auto vwait = [&](uint32_t* base) {       // base = &flags[(t*4+m)*64]
    if (tid < 64) {
      int g = 0;
      for (;;) {
        uint32_t v = aload32(base + tid);
        if (__ballot(v != 0u) == ~0ull) break;
        if (++g > 1000000) break;          // bounded: finish wrong rather than hang
        __builtin_amdgcn_s_sleep(1);
      }
    }
    asm volatile("" ::: "memory");
    __syncthreads();
  };

  auto hbase = [&](f16* buf, int t) -> f16* {
    return buf + (size_t)(t*4 + m) * 32768;
  };
  // fragment read: lane needs h[arow][k..k+7]; k = chunk + kg (8-aligned); plain cacheable
  auto hfrag = [&](const f16* bs, int k) -> f16x8 {
    return *(const f16x8*)(bs + ((size_t)(k >> 3) * 512 + arow * 8));
  };

  // ---- Q(tq) issue: wait h1(tq) flags, load h1 frags + noise ----
  auto q_issue = [&](int tq) {
    vwait(flagsB + (size_t)(tq*4 + m) * 64);
    const f16* hb = hbase(h1blk, tq);
    #pragma unroll
    for (int q_ = 0; q_ < 8; ++q_) {
      h1cf[2*q_]     = hfrag(hb, q_*64 + kg);
      h1cf[2*q_ + 1] = hfrag(hb, q_*64 + 32 + kg);
    }
    if (M >= 1) {
      const float* npp = noise_pre + ((size_t)tq*256 + m*64 + mu*16 + crow)*128 + nu*64 + ra;
      #pragma unroll
      for (int n_ = 0; n_ < 4; ++n_)
        #pragma unroll
        for (int r = 0; r < 4; ++r) nzv[n_][r] = npp[(size_t)r*128 + n_*16];
    }
  };

  // ---- Q(tq) compute: barrier-free GEMM + gumbel softmax -> ctl + out row ----
  auto qblock = [&](int tq) {
    const f16* wq = Wlc + (size_t)(nu*64 + ra) * 512 + kg;
    f32x4 accq[4] = {{0,0,0,0},{0,0,0,0},{0,0,0,0},{0,0,0,0}};
    #pragma unroll
    for (int j = 0; j < 8; ++j) {
      f16x8 ae = h1cf[2*j], ao = h1cf[2*j + 1];
      #pragma unroll
      for (int n_ = 0; n_ < 4; ++n_) {
        f16x8 bE = *(const f16x8*)(wq + (size_t)n_*8192 + j*64);
        f16x8 bO = *(const f16x8*)(wq + (size_t)n_*8192 + j*64 + 32);
        accq[n_] = __builtin_amdgcn_mfma_f32_16x16x32_f16(ae, bE, accq[n_], 0, 0, 0);
        accq[n_] = __builtin_amdgcn_mfma_f32_16x16x32_f16(ao, bO, accq[n_], 0, 0, 0);
      }
    }
    #pragma unroll
    for (int n_ = 0; n_ < 4; ++n_) {
      const int qc = nu*64 + n_*16 + ra;
      #pragma unroll
      for (int r = 0; r < 4; ++r) {
        const int rl = mu*16 + crow + r;
        float g;
        if (M >= 1) g = nzv[n_][r];
        else {
          const uint32_t nidx = (((uint32_t)tq * 256u + (uint32_t)(m*64 + rl)) * 128u + (uint32_t)qc);
          g = gumbel_noise(nidx, true);
        }
        float v = (accq[n_][r] + blv[n_] + g) * 10.0f;
        float mx = v;
        #pragma unroll
        for (int k_ = 1; k_ < 16; k_ <<= 1) mx = fmaxf(mx, __shfl_xor(mx, k_));
        float ex = __expf(v - mx);
        float sm = ex;
        #pragma unroll
        for (int k_ = 1; k_ < 16; k_ <<= 1) sm += __shfl_xor(sm, k_);
        float y = ex * __builtin_amdgcn_rcpf(sm);
        ctl[rl][qc] = (f16)y;
      }
    }
    __syncthreads();   // ctl final (cross-wave for L0 partB + out row)
    if (tid < 128)
      out[((size_t)(m*64 + s) * TT + tq) * 128 + tid] = (float)ctl[s][tid];
  };

  // ---- layer epilogue: acc -> glds -> cell -> coalesced publish + ONE flag store ----
  auto epilogue = [&](int L, float& ca, float& cb, f16* blkbuf, int t, uint32_t* slot) {
    f32x4 av = acce + acco;
    #pragma unroll
    for (int r = 0; r < 4; ++r)
      glds[mu*16 + crow + r][nu*16 + ra] = av[r];     // C/D: col=lane&15, row=(lane>>4)*4+r
    __syncthreads();
    if (tid < 256) {
      const int h2 = hc2 * 2;
      float ia = glds[erow][h2]      + bls[L][0][h2];
      float ib = glds[erow][h2 + 1]  + bls[L][0][h2 + 1];
      float fa = glds[erow][8 + h2]  + bls[L][1][h2];
      float fb = glds[erow][9 + h2]  + bls[L][1][h2 + 1];
      float ga = glds[erow][16 + h2] + bls[L][2][h2];
      float gb = glds[erow][17 + h2] + bls[L][2][h2 + 1];
      float oa = glds[erow][24 + h2] + bls[L][3][h2];
      float ob = glds[erow][25 + h2] + bls[L][3][h2 + 1];
      float cna = fsig(fa) * ca + fsig(ia) * ftanh(ga);
      float cnb = fsig(fb) * cb + fsig(ib) * ftanh(gb);
      ca = cna; cb = cnb;
      union { f16 h[2]; uint32_t u; } pk;
      pk.h[0] = (f16)(fsig(oa) * ftanh(cna));
      pk.h[1] = (f16)(fsig(ob) * ftanh(cnb));
      uint32_t* pb = (uint32_t*)(hbase(blkbuf, t) + (size_t)s * 512);
      astore32(pb + erow*4 + hc2, pk.u);              // write-through publish (1 KB/block)
    }
    asm volatile("s_waitcnt vmcnt(0)" ::: "memory");
    __syncthreads();
    if (tid == 0) astore32(slot, 1u);                 // parallel flag store (no RMW)
  };

  // ==================== main recurrence ====================
  for (int t = 0; t < TT; ++t) {
    // x fragment loads: f16 slabs (M2) or f32 direct (M<2)
    f16x8 xe[4], xo[4];
    if (M >= 2) {
      const f16* xb16 = xf16 + ((size_t)t*4 + m) * 16384;
      #pragma unroll
      for (int j = 0; j < 4; ++j) {
        xe[j] = hfrag(xb16, j*64 + kg);
        xo[j] = hfrag(xb16, j*64 + 32 + kg);
      }
    } else {
      const float* xb = states + ((size_t)(m*64 + arow) * TT + t) * 256;
      #pragma unroll
      for (int j = 0; j < 4; ++j) {
        f32x4 a0 = *(const f32x4*)(xb + j*64 + kg);
        f32x4 a1 = *(const f32x4*)(xb + j*64 + kg + 4);
        f32x4 b0 = *(const f32x4*)(xb + j*64 + 32 + kg);
        f32x4 b1 = *(const f32x4*)(xb + j*64 + 32 + kg + 4);
        xe[j] = cvt8(a0, a1);
        xo[j] = cvt8(b0, b1);
      }
    }

    // Q(t-1) issue: wait + h1 frag loads (latency hides under L0 partA)
    if (t > 0) q_issue(t - 1);

    // ---- L0 partA: chunks 0..3 (x), 4..11 (h0p regs) — barrier-free ----
    acce = f32x4{0,0,0,0}; acco = f32x4{0,0,0,0};
    #pragma unroll
    for (int j = 0; j < 4; ++j)
      MFMA_PAIR(xe[j], xo[j], W0s[nu*16 + ra], j*64)
    #pragma unroll
    for (int j = 4; j < 12; ++j)
      MFMA_PAIR(h0p[2*(j-4)], h0p[2*(j-4) + 1], W0s[nu*16 + ra], j*64)

    // ---- Q(t-1) compute (fills ctl); t=0 keeps one-hot ctl ----
    if (t > 0) qblock(t - 1);

    // ---- L0 partB: ct chunks 12..13 from ctl (LDS frags) ----
    {
      f16x8 ae = *(const f16x8*)&ctl[arow][kg];
      f16x8 ao = *(const f16x8*)&ctl[arow][32 + kg];
      MFMA_PAIR(ae, ao, W0s[nu*16 + ra], 768)
      ae = *(const f16x8*)&ctl[arow][64 + kg];
      ao = *(const f16x8*)&ctl[arow][96 + kg];
      MFMA_PAIR(ae, ao, W0s[nu*16 + ra], 832)
    }
    epilogue(0, c0a, c0b, h0blk, t, flagsA + (size_t)(t*4 + m)*64 + s);

    // ---- L1 part1: chunks 0..7 (h1cf regs) — barrier-free ----
    acce = f32x4{0,0,0,0}; acco = f32x4{0,0,0,0};
    #pragma unroll
    for (int j = 0; j < 8; ++j)
      MFMA_PAIR(h1cf[2*j], h1cf[2*j + 1], W1s[nu*16 + ra], j*64)

    // ---- wait h0(t) flags, load h0 frags (also next step's h0_prev) ----
    vwait(flagsA + (size_t)(t*4 + m)*64);
    {
      const f16* hb0 = hbase(h0blk, t);
      #pragma unroll
      for (int q_ = 0; q_ < 8; ++q_) {
        h0p[2*q_]     = hfrag(hb0, q_*64 + kg);
        h0p[2*q_ + 1] = hfrag(hb0, q_*64 + 32 + kg);
      }
    }
    // ---- L1 part2: chunks 8..15 (h0 frags) ----
    #pragma unroll
    for (int j = 8; j < 16; ++j)
      MFMA_PAIR(h0p[2*(j-8)], h0p[2*(j-8) + 1], W1s[nu*16 + ra], j*64)

    epilogue(1, c1a, c1b, h1blk, t, flagsB + (size_t)(t*4 + m)*64 + s);
  }

  // ---- tail: Q for t = TT-1 ----
  q_issue(TT - 1);
  qblock(TT - 1);
}

// ---------------- host ----------------
extern "C" void kernel_launch(void* const* d_in, const int* in_sizes, int n_in,
                              void* d_out, int out_size, void* d_ws, size_t ws_size,
                              hipStream_t stream) {
  const float* states = (const float*)d_in[0];
  const float* Wih0 = (const float*)d_in[1];
  const float* Whh0 = (const float*)d_in[2];
  const float* bih0 = (const float*)d_in[3];
  const float* bhh0 = (const float*)d_in[4];
  const float* Wih1 = (const float*)d_in[5];
  const float* Whh1 = (const float*)d_in[6];
  const float* bih1 = (const float*)d_in[7];
  const float* bhh1 = (const float*)d_in[8];
  const float* Wlin = (const float*)d_in[9];
  const float* blin = (const float*)d_in[10];
  float* out = (float*)d_out;
  (void)in_sizes; (void)n_in; (void)out_size;

  char* ws = (char*)d_ws;
  uint32_t* flagsA = (uint32_t*)ws;                         // [512][4][64] u32 = 524,288 B
  uint32_t* flagsB = (uint32_t*)(ws + 524288);              // 524,288 B
  uint32_t* cnt0   = (uint32_t*)(ws + 1048576);             // 256 B pad
  const size_t cnt_bytes = 1048832;                         // memset region
  f16* Wlc = (f16*)(ws + cnt_bytes);                        // 131,072 B
  char* p = ws + cnt_bytes + 131072;

  const size_t hist_bytes = (size_t)TT * 4 * 32768;         // 67,108,864 per layer (f16 = 2B: 512*4*64*512*2)
  f16* h0b = (f16*)p;                                       // 512*4*32768 f16 = 134,217,728 B
  f16* h1b = (f16*)(p + 134217728);
  float* noise = (float*)(p + 2ull*134217728);              // 67,108,864 B
  f16* xf16 = (f16*)(p + 2ull*134217728 + 67108864);        // 67,108,864 B

  const size_t need0 = cnt_bytes + 131072 + 2ull*134217728;              // ~269.6 MB
  const size_t need1 = need0 + 67108864;                                 // ~336.7 MB
  const size_t need2 = need1 + 67108864;                                 // ~403.8 MB
  (void)hist_bytes;

  hipMemsetAsync(ws, 0, cnt_bytes, stream);
  if (ws_size >= need2) {
    persistent_kernel<2><<<256, 512, 0, stream>>>(
        states, Wih0, Whh0, bih0, bhh0, Wih1, Whh1, bih1, bhh1, Wlin, blin,
        out, cnt0, flagsA, flagsB, h0b, h1b, Wlc, noise, xf16);
  } else if (ws_size >= need1) {
    persistent_kernel<1><<<256, 512, 0, stream>>>(
        states, Wih0, Whh0, bih0, bhh0, Wih1, Whh1, bih1, bhh1, Wlin, blin,
        out, cnt0, flagsA, flagsB, h0b, h1b, Wlc, noise, nullptr);
  } else {
    persistent_kernel<0><<<256, 512, 0, stream>>>(
        states, Wih0, Whh0, bih0, bhh0, Wih1, Whh1, bih1, bhh1, Wlin, blin,
        out, cnt0, flagsA, flagsB, h0b, h1b, Wlc, nullptr, nullptr);
  }
}

// Round 11
// 8222.600 us; speedup vs baseline: 2.5375x; 2.0638x over previous
//
#include <hip/hip_runtime.h>
#include <cstdint>
#include <cstddef>

// Problem constants
#define BB 256     // batch
#define TT 512     // time steps
#define HH 512     // hidden
// 256 blocks = 4 m-groups (64 rows) x 64 s-slices (8 hcols = 32 gatecols/layer), 512 thr.
// R11 = R10 + issued-bandwidth attack:
//  (1) h slabs staged via LDS in 16KB quarters (read once per block, coalesced), fragment
//      extraction via ds_read; h issued 256->128 KB/block/step.
//  (2) Q remapped: wave w owns cols [w*16,w*16+16), loops mu over all 64 rows with A-frags
//      from the staged LDS slab -> Wlc B-traffic 512->128 KB/block/step (4x cut).
// Everything else identical to R10 (t-indexed slabs, vector flags, xf16 table, reg carries).

typedef _Float16 f16;
typedef _Float16 f16x8 __attribute__((ext_vector_type(8)));
typedef float f32x4 __attribute__((ext_vector_type(4)));

// ---------------- threefry2x32 (key = (0,42)), jax_threefry_partitionable ----------------
__device__ __forceinline__ void tf_round(uint32_t& x0, uint32_t& x1, const int r) {
  x0 += x1;
  x1 = (x1 << r) | (x1 >> (32 - r));
  x1 ^= x0;
}

__device__ __forceinline__ void threefry2x32(uint32_t c0, uint32_t c1, uint32_t& o0, uint32_t& o1) {
  const uint32_t ks0 = 0u, ks1 = 42u;
  const uint32_t ks2 = 0x1BD11BDAu ^ ks0 ^ ks1;
  uint32_t x0 = c0 + ks0, x1 = c1 + ks1;
  tf_round(x0,x1,13); tf_round(x0,x1,15); tf_round(x0,x1,26); tf_round(x0,x1,6);
  x0 += ks1; x1 += ks2 + 1u;
  tf_round(x0,x1,17); tf_round(x0,x1,29); tf_round(x0,x1,16); tf_round(x0,x1,24);
  x0 += ks2; x1 += ks0 + 2u;
  tf_round(x0,x1,13); tf_round(x0,x1,15); tf_round(x0,x1,26); tf_round(x0,x1,6);
  x0 += ks0; x1 += ks1 + 3u;
  tf_round(x0,x1,17); tf_round(x0,x1,29); tf_round(x0,x1,16); tf_round(x0,x1,24);
  x0 += ks1; x1 += ks2 + 4u;
  tf_round(x0,x1,13); tf_round(x0,x1,15); tf_round(x0,x1,26); tf_round(x0,x1,6);
  x0 += ks2; x1 += ks0 + 5u;
  o0 = x0; o1 = x1;
}

__device__ __forceinline__ float gumbel_noise(uint32_t idx, bool fast) {
  uint32_t o0, o1;
  threefry2x32(0u, idx, o0, o1);
  uint32_t bits = o0 ^ o1;
  uint32_t fb = (bits >> 9) | 0x3f800000u;
  float u = __uint_as_float(fb) - 1.0f;
  const float tiny = 1.17549435e-38f;
  u = fmaxf(tiny, u + tiny);
  if (fast) return -__logf(-__logf(u));
  return -logf(-logf(u));
}

// ---------------- fast transcendentals (err ~1e-6, tolerance 2e-2) ----------------
__device__ __forceinline__ float fsig(float x) {
  return __builtin_amdgcn_rcpf(1.0f + __expf(-x));
}
__device__ __forceinline__ float ftanh(float x) {
  float xx = fminf(fmaxf(x, -15.f), 15.f);
  float t = __expf(2.f * xx);
  return (t - 1.f) * __builtin_amdgcn_rcpf(t + 1.f);
}

// ---------------- atomics (relaxed agent) ----------------
__device__ __forceinline__ uint32_t aload32(const uint32_t* p) {
  return __hip_atomic_load(p, __ATOMIC_RELAXED, __HIP_MEMORY_SCOPE_AGENT);
}
__device__ __forceinline__ void astore32(uint32_t* p, uint32_t v) {
  __hip_atomic_store(p, v, __ATOMIC_RELAXED, __HIP_MEMORY_SCOPE_AGENT);
}

__device__ __forceinline__ f16x8 cvt8(f32x4 a, f32x4 b) {
  f16x8 w;
  w[0]=(f16)a[0]; w[1]=(f16)a[1]; w[2]=(f16)a[2]; w[3]=(f16)a[3];
  w[4]=(f16)b[0]; w[5]=(f16)b[1]; w[6]=(f16)b[2]; w[7]=(f16)b[3];
  return w;
}

#define MFMA_PAIR(AE, AO, WROW, KOFF) { \
  f16x8 be_ = *(const f16x8*)&(WROW)[(KOFF) + kg]; \
  f16x8 bo_ = *(const f16x8*)&(WROW)[(KOFF) + 32 + kg]; \
  acce = __builtin_amdgcn_mfma_f32_16x16x32_f16((AE), be_, acce, 0, 0, 0); \
  acco = __builtin_amdgcn_mfma_f32_16x16x32_f16((AO), bo_, acco, 0, 0, 0); }

// ---------------- the persistent kernel ----------------
template<bool PRE>
__global__ __launch_bounds__(512, 1) void persistent_kernel(
    const float* __restrict__ states,
    const float* __restrict__ Wih0, const float* __restrict__ Whh0,
    const float* __restrict__ bih0, const float* __restrict__ bhh0,
    const float* __restrict__ Wih1, const float* __restrict__ Whh1,
    const float* __restrict__ bih1, const float* __restrict__ bhh1,
    const float* __restrict__ Wlin, const float* __restrict__ blin,
    float* __restrict__ out,
    uint32_t* cnt0, uint32_t* flagsA, uint32_t* flagsB,
    f16* h0blk, f16* h1blk, f16* Wlc, float* noise_pre, f16* xf16)
{
  __shared__ __align__(16) f16 W0s[32][904];    // 57,856 B
  __shared__ __align__(16) f16 W1s[32][1032];   // 66,048 B
  __shared__ __align__(16) f16 ctl[64][136];    // 17,408 B
  __shared__ __align__(16) f16 hstg[16][520];   // 16,640 B (h slab quarter, padded)
  __shared__ float bls[2][4][8];                //    256 B  (total ~158 KB)
  float (*glds)[37] = reinterpret_cast<float(*)[37]>(&hstg[0][0]);   // 9,472 B overlay

  const int tid = threadIdx.x;
  const int bid = blockIdx.x;
  const int m = bid & 3;            // m-group (64 batch rows)
  const int s = bid >> 2;           // h-col slice 0..63 (8 cols)
  const int lane = tid & 63;
  const int wv = tid >> 6;
  const int mu = wv >> 1;           // L0/L1: 16-row tile
  const int nu = wv & 1;            // L0/L1: 16-gatecol tile
  const int ra = lane & 15;
  const int kg = (lane >> 4) << 3;
  const int crow = (lane >> 4) << 2;
  const int arow = mu * 16 + ra;    // own A-fragment row for L0/L1
  const int cw = wv * 16;           // Q: this wave's col-tile base (0..112)
  const int erow = tid >> 2;        // cell row (tid<256)
  const int hc2 = tid & 3;          // cell hcol pair index

  // ---- one-time LDS W init (f32 -> f16, reordered K) ----
  {
    const int lc = tid & 31;
    const int gr = ((lc >> 3) << 9) + s*8 + (lc & 7);   // gate*512 + hcol
    for (int k = tid >> 5; k < 896; k += 16) {
      float v;
      if (k < 256)      v = Wih0[(size_t)gr * 384 + k];              // x
      else if (k < 768) v = Whh0[(size_t)gr * 512 + (k - 256)];      // h0_prev
      else              v = Wih0[(size_t)gr * 384 + 256 + (k - 768)];// ct
      W0s[lc][k] = (f16)v;
    }
    for (int k = tid >> 5; k < 1024; k += 16) {
      float v = (k < 512) ? Whh1[(size_t)gr * 512 + k]               // h1_prev
                          : Wih1[(size_t)gr * 512 + (k - 512)];      // h0_cur
      W1s[lc][k] = (f16)v;
    }
  }
  for (int e = tid; e < 64 * 128; e += 512)
    ctl[e >> 7][e & 127] = (f16)(((e & 15) == 0) ? 1.f : 0.f);
  if (tid < 64) {
    const int l = tid >> 5, g = (tid >> 3) & 3, hc = tid & 7;
    const int col = g * 512 + s*8 + hc;
    bls[l][g][hc] = l ? (bih1[col] + bhh1[col]) : (bih0[col] + bhh0[col]);
  }

  // ---- global init (plain stores; flushed by startup RELEASE) ----
  if (tid < 128) {
    const int e2 = bid * 128 + tid;
    union { f16 h[2]; uint32_t u; } pk2;
    pk2.h[0] = (f16)Wlin[2*e2]; pk2.h[1] = (f16)Wlin[2*e2 + 1];
    ((uint32_t*)Wlc)[e2] = pk2.u;
  }
  if (PRE) {
    const uint32_t base = (uint32_t)bid * 65536u;
    for (uint32_t e = tid; e < 65536u; e += 512u)
      noise_pre[base + e] = gumbel_noise(base + e, false);
    // x -> f16 fragment-layout slabs [t][m][16384]
    #pragma unroll
    for (int tt2 = 0; tt2 < 2; ++tt2) {
      const int tx = bid * 2 + tt2;
      const int r = tid >> 3;
      const int kb = (tid & 7) * 32;
      #pragma unroll
      for (int mm = 0; mm < 4; ++mm) {
        const float* src = states + ((size_t)(mm*64 + r) * TT + tx) * 256 + kb;
        f16* dst = xf16 + ((size_t)tx*4 + mm) * 16384;
        #pragma unroll
        for (int j = 0; j < 4; ++j) {
          f32x4 a = *(const f32x4*)(src + j*8);
          f32x4 b = *(const f32x4*)(src + j*8 + 4);
          *(f16x8*)(dst + (size_t)((kb + j*8) >> 3) * 512 + r*8) = cvt8(a, b);
        }
      }
    }
  }
  // ---- startup barrier: the ONLY cache-maintaining release/acquire ----
  __syncthreads();
  if (tid == 0) {
    __hip_atomic_fetch_add(cnt0, 1u, __ATOMIC_RELEASE, __HIP_MEMORY_SCOPE_AGENT);
    int g = 0;
    while (aload32(cnt0) < 256u && g < 2000000) { __builtin_amdgcn_s_sleep(1); ++g; }
    (void)__hip_atomic_load(cnt0, __ATOMIC_ACQUIRE, __HIP_MEMORY_SCOPE_AGENT);
  }
  __syncthreads();

  // ---- per-thread constants / state ----
  const float blq = blin[cw + ra];                    // Q bias (one col per lane)
  float c0a = 0.f, c0b = 0.f, c1a = 0.f, c1b = 0.f;

  f16x8 h0p[16], h1cf[16];
  #pragma unroll
  for (int q_ = 0; q_ < 16; ++q_) { h0p[q_] = f16x8{}; h1cf[q_] = f16x8{}; }
  f32x4 acce, acco;

  auto vwait = [&](uint32_t* base) {
    if (tid < 64) {
      int g = 0;
      for (;;) {
        uint32_t v = aload32(base + tid);
        if (__ballot(v != 0u) == ~0ull) break;
        if (++g > 1000000) break;
        __builtin_amdgcn_s_sleep(2);
      }
    }
    asm volatile("" ::: "memory");
    __syncthreads();
  };

  // stage one 16KB quarter (8192 f16) of a 64KB slab into hstg, coalesced
  auto stage_quarter = [&](const f16* slab, int q) {
    const f16* src = slab + q * 8192;
    f16x8 a = *(const f16x8*)(src + tid*8);
    f16x8 b = *(const f16x8*)(src + 4096 + tid*8);
    *(f16x8*)&hstg[tid >> 6][(tid & 63) * 8] = a;
    *(f16x8*)&hstg[8 + (tid >> 6)][(tid & 63) * 8] = b;
  };
  // fragment from staged quarter: row (0..63), kloc (0..127, 8-aligned)
  auto lfrag = [&](int row, int kloc) -> f16x8 {
    return *(const f16x8*)&hstg[kloc >> 3][row * 8];
  };

  // ---- Q phase for tq: wait h1(tq), stage slab quarters, Q GEMM (remapped), softmax ----
  auto q_phase = [&](int tq) {
    float nzq[4][4];
    if (PRE) {
      const float* np0 = noise_pre + ((size_t)tq*256 + m*64 + crow) * 128 + cw + ra;
      #pragma unroll
      for (int mu2 = 0; mu2 < 4; ++mu2)
        #pragma unroll
        for (int r = 0; r < 4; ++r)
          nzq[mu2][r] = np0[(size_t)(mu2*16 + r) * 128];
    }
    vwait(flagsB + (size_t)(tq*4 + m) * 64);
    const f16* hb = h1blk + ((size_t)tq*4 + m) * 32768;
    f32x4 accq[4] = {{0,0,0,0},{0,0,0,0},{0,0,0,0},{0,0,0,0}};
    #pragma unroll
    for (int q = 0; q < 4; ++q) {
      if (q) __syncthreads();                  // prior quarter's reads done
      stage_quarter(hb, q);
      __syncthreads();
      // own-arow h1 frags (L1 part1 operands): chunks 2q, 2q+1
      h1cf[4*q]     = lfrag(arow, kg);
      h1cf[4*q + 1] = lfrag(arow, 32 + kg);
      h1cf[4*q + 2] = lfrag(arow, 64 + kg);
      h1cf[4*q + 3] = lfrag(arow, 96 + kg);
      // Q GEMM quarter: wave covers cols cw..cw+15 x all 64 rows
      #pragma unroll
      for (int jj = 0; jj < 2; ++jj) {
        const f16* wqp = Wlc + (size_t)(cw + ra) * 512 + (q*2 + jj) * 64;
        f16x8 bE = *(const f16x8*)(wqp + kg);
        f16x8 bO = *(const f16x8*)(wqp + 32 + kg);
        #pragma unroll
        for (int mu2 = 0; mu2 < 4; ++mu2) {
          f16x8 ae = lfrag(mu2*16 + ra, jj*64 + kg);
          f16x8 ao = lfrag(mu2*16 + ra, jj*64 + 32 + kg);
          accq[mu2] = __builtin_amdgcn_mfma_f32_16x16x32_f16(ae, bE, accq[mu2], 0, 0, 0);
          accq[mu2] = __builtin_amdgcn_mfma_f32_16x16x32_f16(ao, bO, accq[mu2], 0, 0, 0);
        }
      }
    }
    __syncthreads();                           // hstg reads done
    // softmax: C/D layout row = crow + r (within mu2 tile), col = ra
    #pragma unroll
    for (int mu2 = 0; mu2 < 4; ++mu2) {
      #pragma unroll
      for (int r = 0; r < 4; ++r) {
        const int row = mu2*16 + crow + r;
        const int col = cw + ra;
        float g;
        if (PRE) g = nzq[mu2][r];
        else g = gumbel_noise(((uint32_t)tq*256u + (uint32_t)(m*64 + row)) * 128u + (uint32_t)col, true);
        float v = (accq[mu2][r] + blq + g) * 10.0f;
        float mx = v;
        #pragma unroll
        for (int k_ = 1; k_ < 16; k_ <<= 1) mx = fmaxf(mx, __shfl_xor(mx, k_));
        float ex = __expf(v - mx);
        float sm = ex;
        #pragma unroll
        for (int k_ = 1; k_ < 16; k_ <<= 1) sm += __shfl_xor(sm, k_);
        ctl[row][col] = (f16)(ex * __builtin_amdgcn_rcpf(sm));
      }
    }
    __syncthreads();                           // ctl final
    if (tid < 128)
      out[((size_t)(m*64 + s) * TT + tq) * 128 + tid] = (float)ctl[s][tid];
  };

  // ---- layer epilogue: acc -> glds(overlay) -> cell -> coalesced publish + flag ----
  auto epilogue = [&](int L, float& ca, float& cb, f16* blkbuf, int t, uint32_t* slot) {
    f32x4 av = acce + acco;
    #pragma unroll
    for (int r = 0; r < 4; ++r)
      glds[mu*16 + crow + r][nu*16 + ra] = av[r];
    __syncthreads();
    if (tid < 256) {
      const int h2 = hc2 * 2;
      float ia = glds[erow][h2]      + bls[L][0][h2];
      float ib = glds[erow][h2 + 1]  + bls[L][0][h2 + 1];
      float fa = glds[erow][8 + h2]  + bls[L][1][h2];
      float fb = glds[erow][9 + h2]  + bls[L][1][h2 + 1];
      float ga = glds[erow][16 + h2] + bls[L][2][h2];
      float gb = glds[erow][17 + h2] + bls[L][2][h2 + 1];
      float oa = glds[erow][24 + h2] + bls[L][3][h2];
      float ob = glds[erow][25 + h2] + bls[L][3][h2 + 1];
      float cna = fsig(fa) * ca + fsig(ia) * ftanh(ga);
      float cnb = fsig(fb) * cb + fsig(ib) * ftanh(gb);
      ca = cna; cb = cnb;
      union { f16 h[2]; uint32_t u; } pk;
      pk.h[0] = (f16)(fsig(oa) * ftanh(cna));
      pk.h[1] = (f16)(fsig(ob) * ftanh(cnb));
      uint32_t* pb = (uint32_t*)(blkbuf + ((size_t)t*4 + m) * 32768 + (size_t)s * 512);
      astore32(pb + erow*4 + hc2, pk.u);
    }
    asm volatile("s_waitcnt vmcnt(0)" ::: "memory");
    __syncthreads();
    if (tid == 0) astore32(slot, 1u);
  };

  // ==================== main recurrence ====================
  for (int t = 0; t < TT; ++t) {
    // x frags
    f16x8 xe[4], xo[4];
    if (PRE) {
      const f16* xb16 = xf16 + ((size_t)t*4 + m) * 16384;
      #pragma unroll
      for (int j = 0; j < 4; ++j) {
        xe[j] = *(const f16x8*)(xb16 + (size_t)((j*64 + kg) >> 3) * 512 + arow*8);
        xo[j] = *(const f16x8*)(xb16 + (size_t)((j*64 + 32 + kg) >> 3) * 512 + arow*8);
      }
    } else {
      const float* xb = states + ((size_t)(m*64 + arow) * TT + t) * 256;
      #pragma unroll
      for (int j = 0; j < 4; ++j) {
        f32x4 a0 = *(const f32x4*)(xb + j*64 + kg);
        f32x4 a1 = *(const f32x4*)(xb + j*64 + kg + 4);
        f32x4 b0 = *(const f32x4*)(xb + j*64 + 32 + kg);
        f32x4 b1 = *(const f32x4*)(xb + j*64 + 32 + kg + 4);
        xe[j] = cvt8(a0, a1);
        xo[j] = cvt8(b0, b1);
      }
    }

    // ---- L0 x + h0p chunks (register-only, hide upcoming wait) ----
    acce = f32x4{0,0,0,0}; acco = f32x4{0,0,0,0};
    #pragma unroll
    for (int j = 0; j < 4; ++j)
      MFMA_PAIR(xe[j], xo[j], W0s[nu*16 + ra], j*64)
    #pragma unroll
    for (int j = 4; j < 12; ++j)
      MFMA_PAIR(h0p[2*(j-4)], h0p[2*(j-4) + 1], W0s[nu*16 + ra], j*64)

    // ---- Q(t-1): stages h1(t-1) slab (fills h1cf) + softmax -> ctl ----
    if (t > 0) q_phase(t - 1);

    // ---- L0 partB: ct chunks 12..13 from ctl ----
    {
      f16x8 ae = *(const f16x8*)&ctl[arow][kg];
      f16x8 ao = *(const f16x8*)&ctl[arow][32 + kg];
      MFMA_PAIR(ae, ao, W0s[nu*16 + ra], 768)
      ae = *(const f16x8*)&ctl[arow][64 + kg];
      ao = *(const f16x8*)&ctl[arow][96 + kg];
      MFMA_PAIR(ae, ao, W0s[nu*16 + ra], 832)
    }
    epilogue(0, c0a, c0b, h0blk, t, flagsA + (size_t)(t*4 + m)*64 + s);

    // ---- L1 part1: chunks 0..7 (h1cf regs) ----
    acce = f32x4{0,0,0,0}; acco = f32x4{0,0,0,0};
    #pragma unroll
    for (int j = 0; j < 8; ++j)
      MFMA_PAIR(h1cf[2*j], h1cf[2*j + 1], W1s[nu*16 + ra], j*64)

    // ---- wait h0(t); stage slab quarters -> h0p regs, L1 part2 interleaved ----
    vwait(flagsA + (size_t)(t*4 + m)*64);
    {
      const f16* hb0 = h0blk + ((size_t)t*4 + m) * 32768;
      #pragma unroll
      for (int q = 0; q < 4; ++q) {
        __syncthreads();                       // prior reads (glds/quarter) done
        stage_quarter(hb0, q);
        __syncthreads();
        h0p[4*q]     = lfrag(arow, kg);
        h0p[4*q + 1] = lfrag(arow, 32 + kg);
        h0p[4*q + 2] = lfrag(arow, 64 + kg);
        h0p[4*q + 3] = lfrag(arow, 96 + kg);
        MFMA_PAIR(h0p[4*q],     h0p[4*q + 1], W1s[nu*16 + ra], (8 + 2*q)*64)
        MFMA_PAIR(h0p[4*q + 2], h0p[4*q + 3], W1s[nu*16 + ra], (9 + 2*q)*64)
      }
    }
    __syncthreads();                           // hstg reads done before glds overlay
    epilogue(1, c1a, c1b, h1blk, t, flagsB + (size_t)(t*4 + m)*64 + s);
  }

  // ---- tail: Q for t = TT-1 ----
  q_phase(TT - 1);
}

// ---------------- host ----------------
extern "C" void kernel_launch(void* const* d_in, const int* in_sizes, int n_in,
                              void* d_out, int out_size, void* d_ws, size_t ws_size,
                              hipStream_t stream) {
  const float* states = (const float*)d_in[0];
  const float* Wih0 = (const float*)d_in[1];
  const float* Whh0 = (const float*)d_in[2];
  const float* bih0 = (const float*)d_in[3];
  const float* bhh0 = (const float*)d_in[4];
  const float* Wih1 = (const float*)d_in[5];
  const float* Whh1 = (const float*)d_in[6];
  const float* bih1 = (const float*)d_in[7];
  const float* bhh1 = (const float*)d_in[8];
  const float* Wlin = (const float*)d_in[9];
  const float* blin = (const float*)d_in[10];
  float* out = (float*)d_out;
  (void)in_sizes; (void)n_in; (void)out_size;

  char* ws = (char*)d_ws;
  uint32_t* flagsA = (uint32_t*)ws;                         // [512][4][64] u32 = 524,288 B
  uint32_t* flagsB = (uint32_t*)(ws + 524288);              // 524,288 B
  uint32_t* cnt0   = (uint32_t*)(ws + 1048576);             // 256 B pad
  const size_t cnt_bytes = 1048832;
  f16* Wlc = (f16*)(ws + cnt_bytes);                        // 131,072 B
  char* p = ws + cnt_bytes + 131072;

  f16* h0b = (f16*)p;                                       // 512*4*32768 f16 = 134,217,728 B
  f16* h1b = (f16*)(p + 134217728ull);
  float* noise = (float*)(p + 2ull*134217728);              // 67,108,864 B
  f16* xf16 = (f16*)(p + 2ull*134217728 + 67108864);        // 67,108,864 B

  const size_t need1 = cnt_bytes + 131072 + 2ull*134217728;              // ~269.6 MB
  const size_t need2 = need1 + 2ull*67108864;                            // ~403.8 MB

  hipMemsetAsync(ws, 0, cnt_bytes, stream);
  if (ws_size >= need2) {
    persistent_kernel<true><<<256, 512, 0, stream>>>(
        states, Wih0, Whh0, bih0, bhh0, Wih1, Whh1, bih1, bhh1, Wlin, blin,
        out, cnt0, flagsA, flagsB, h0b, h1b, Wlc, noise, xf16);
  } else {
    persistent_kernel<false><<<256, 512, 0, stream>>>(
        states, Wih0, Whh0, bih0, bhh0, Wih1, Whh1, bih1, bhh1, Wlin, blin,
        out, cnt0, flagsA, flagsB, h0b, h1b, Wlc, nullptr, nullptr);
  }
}

// Round 12
// 6812.521 us; speedup vs baseline: 3.0627x; 1.2070x over previous
//
#include <hip/hip_runtime.h>
#include <cstdint>
#include <cstddef>

// Problem constants
#define BB 256     // batch
#define TT 512     // time steps
#define HH 512     // hidden
// 256 blocks = 4 m-groups (64 rows) x 64 s-slices (8 hcols = 32 gatecols/layer), 512 thr.
// R12 = R11 + staging-latency attack:
//  (1) Q quarters register-prefetched right after vwait(B): only quarter 0's LLC latency
//      exposed; LDS writes come from regs.
//  (2) L1 part2 h0 fragments loaded DIRECTLY from the t-slab (own 16 rows per wave, plain
//      cacheable, R8-verified addressing) -- no LDS staging, no barriers on that path.
//  (3) x(t+1) prefetch issued in the pub0->waitA window (covers hopA instead of adding
//      consumer-side latency).
// Everything else identical to R11.

typedef _Float16 f16;
typedef _Float16 f16x8 __attribute__((ext_vector_type(8)));
typedef float f32x4 __attribute__((ext_vector_type(4)));

// ---------------- threefry2x32 (key = (0,42)), jax_threefry_partitionable ----------------
__device__ __forceinline__ void tf_round(uint32_t& x0, uint32_t& x1, const int r) {
  x0 += x1;
  x1 = (x1 << r) | (x1 >> (32 - r));
  x1 ^= x0;
}

__device__ __forceinline__ void threefry2x32(uint32_t c0, uint32_t c1, uint32_t& o0, uint32_t& o1) {
  const uint32_t ks0 = 0u, ks1 = 42u;
  const uint32_t ks2 = 0x1BD11BDAu ^ ks0 ^ ks1;
  uint32_t x0 = c0 + ks0, x1 = c1 + ks1;
  tf_round(x0,x1,13); tf_round(x0,x1,15); tf_round(x0,x1,26); tf_round(x0,x1,6);
  x0 += ks1; x1 += ks2 + 1u;
  tf_round(x0,x1,17); tf_round(x0,x1,29); tf_round(x0,x1,16); tf_round(x0,x1,24);
  x0 += ks2; x1 += ks0 + 2u;
  tf_round(x0,x1,13); tf_round(x0,x1,15); tf_round(x0,x1,26); tf_round(x0,x1,6);
  x0 += ks0; x1 += ks1 + 3u;
  tf_round(x0,x1,17); tf_round(x0,x1,29); tf_round(x0,x1,16); tf_round(x0,x1,24);
  x0 += ks1; x1 += ks2 + 4u;
  tf_round(x0,x1,13); tf_round(x0,x1,15); tf_round(x0,x1,26); tf_round(x0,x1,6);
  x0 += ks2; x1 += ks0 + 5u;
  o0 = x0; o1 = x1;
}

__device__ __forceinline__ float gumbel_noise(uint32_t idx, bool fast) {
  uint32_t o0, o1;
  threefry2x32(0u, idx, o0, o1);
  uint32_t bits = o0 ^ o1;
  uint32_t fb = (bits >> 9) | 0x3f800000u;
  float u = __uint_as_float(fb) - 1.0f;
  const float tiny = 1.17549435e-38f;
  u = fmaxf(tiny, u + tiny);
  if (fast) return -__logf(-__logf(u));
  return -logf(-logf(u));
}

// ---------------- fast transcendentals (err ~1e-6, tolerance 2e-2) ----------------
__device__ __forceinline__ float fsig(float x) {
  return __builtin_amdgcn_rcpf(1.0f + __expf(-x));
}
__device__ __forceinline__ float ftanh(float x) {
  float xx = fminf(fmaxf(x, -15.f), 15.f);
  float t = __expf(2.f * xx);
  return (t - 1.f) * __builtin_amdgcn_rcpf(t + 1.f);
}

// ---------------- atomics (relaxed agent) ----------------
__device__ __forceinline__ uint32_t aload32(const uint32_t* p) {
  return __hip_atomic_load(p, __ATOMIC_RELAXED, __HIP_MEMORY_SCOPE_AGENT);
}
__device__ __forceinline__ void astore32(uint32_t* p, uint32_t v) {
  __hip_atomic_store(p, v, __ATOMIC_RELAXED, __HIP_MEMORY_SCOPE_AGENT);
}

__device__ __forceinline__ f16x8 cvt8(f32x4 a, f32x4 b) {
  f16x8 w;
  w[0]=(f16)a[0]; w[1]=(f16)a[1]; w[2]=(f16)a[2]; w[3]=(f16)a[3];
  w[4]=(f16)b[0]; w[5]=(f16)b[1]; w[6]=(f16)b[2]; w[7]=(f16)b[3];
  return w;
}

#define MFMA_PAIR(AE, AO, WROW, KOFF) { \
  f16x8 be_ = *(const f16x8*)&(WROW)[(KOFF) + kg]; \
  f16x8 bo_ = *(const f16x8*)&(WROW)[(KOFF) + 32 + kg]; \
  acce = __builtin_amdgcn_mfma_f32_16x16x32_f16((AE), be_, acce, 0, 0, 0); \
  acco = __builtin_amdgcn_mfma_f32_16x16x32_f16((AO), bo_, acco, 0, 0, 0); }

// ---------------- the persistent kernel ----------------
template<bool PRE>
__global__ __launch_bounds__(512, 1) void persistent_kernel(
    const float* __restrict__ states,
    const float* __restrict__ Wih0, const float* __restrict__ Whh0,
    const float* __restrict__ bih0, const float* __restrict__ bhh0,
    const float* __restrict__ Wih1, const float* __restrict__ Whh1,
    const float* __restrict__ bih1, const float* __restrict__ bhh1,
    const float* __restrict__ Wlin, const float* __restrict__ blin,
    float* __restrict__ out,
    uint32_t* cnt0, uint32_t* flagsA, uint32_t* flagsB,
    f16* h0blk, f16* h1blk, f16* Wlc, float* noise_pre, f16* xf16)
{
  __shared__ __align__(16) f16 W0s[32][904];    // 57,856 B
  __shared__ __align__(16) f16 W1s[32][1032];   // 66,048 B
  __shared__ __align__(16) f16 ctl[64][136];    // 17,408 B
  __shared__ __align__(16) f16 hstg[16][520];   // 16,640 B (h1 slab quarter for Q)
  __shared__ float bls[2][4][8];                //    256 B  (total ~158 KB)
  float (*glds)[37] = reinterpret_cast<float(*)[37]>(&hstg[0][0]);   // 9,472 B overlay

  const int tid = threadIdx.x;
  const int bid = blockIdx.x;
  const int m = bid & 3;            // m-group (64 batch rows)
  const int s = bid >> 2;           // h-col slice 0..63 (8 cols)
  const int lane = tid & 63;
  const int wv = tid >> 6;
  const int mu = wv >> 1;           // L0/L1: 16-row tile
  const int nu = wv & 1;            // L0/L1: 16-gatecol tile
  const int ra = lane & 15;
  const int kg = (lane >> 4) << 3;
  const int crow = (lane >> 4) << 2;
  const int arow = mu * 16 + ra;    // own A-fragment row for L0/L1
  const int cw = wv * 16;           // Q: this wave's col-tile base (0..112)
  const int erow = tid >> 2;        // cell row (tid<256)
  const int hc2 = tid & 3;          // cell hcol pair index

  // ---- one-time LDS W init (f32 -> f16, reordered K) ----
  {
    const int lc = tid & 31;
    const int gr = ((lc >> 3) << 9) + s*8 + (lc & 7);   // gate*512 + hcol
    for (int k = tid >> 5; k < 896; k += 16) {
      float v;
      if (k < 256)      v = Wih0[(size_t)gr * 384 + k];              // x
      else if (k < 768) v = Whh0[(size_t)gr * 512 + (k - 256)];      // h0_prev
      else              v = Wih0[(size_t)gr * 384 + 256 + (k - 768)];// ct
      W0s[lc][k] = (f16)v;
    }
    for (int k = tid >> 5; k < 1024; k += 16) {
      float v = (k < 512) ? Whh1[(size_t)gr * 512 + k]               // h1_prev
                          : Wih1[(size_t)gr * 512 + (k - 512)];      // h0_cur
      W1s[lc][k] = (f16)v;
    }
  }
  for (int e = tid; e < 64 * 128; e += 512)
    ctl[e >> 7][e & 127] = (f16)(((e & 15) == 0) ? 1.f : 0.f);
  if (tid < 64) {
    const int l = tid >> 5, g = (tid >> 3) & 3, hc = tid & 7;
    const int col = g * 512 + s*8 + hc;
    bls[l][g][hc] = l ? (bih1[col] + bhh1[col]) : (bih0[col] + bhh0[col]);
  }

  // ---- global init (plain stores; flushed by startup RELEASE) ----
  if (tid < 128) {
    const int e2 = bid * 128 + tid;
    union { f16 h[2]; uint32_t u; } pk2;
    pk2.h[0] = (f16)Wlin[2*e2]; pk2.h[1] = (f16)Wlin[2*e2 + 1];
    ((uint32_t*)Wlc)[e2] = pk2.u;
  }
  if (PRE) {
    const uint32_t base = (uint32_t)bid * 65536u;
    for (uint32_t e = tid; e < 65536u; e += 512u)
      noise_pre[base + e] = gumbel_noise(base + e, false);
    // x -> f16 fragment-layout slabs [t][m][16384]
    #pragma unroll
    for (int tt2 = 0; tt2 < 2; ++tt2) {
      const int tx = bid * 2 + tt2;
      const int r = tid >> 3;
      const int kb = (tid & 7) * 32;
      #pragma unroll
      for (int mm = 0; mm < 4; ++mm) {
        const float* src = states + ((size_t)(mm*64 + r) * TT + tx) * 256 + kb;
        f16* dst = xf16 + ((size_t)tx*4 + mm) * 16384;
        #pragma unroll
        for (int j = 0; j < 4; ++j) {
          f32x4 a = *(const f32x4*)(src + j*8);
          f32x4 b = *(const f32x4*)(src + j*8 + 4);
          *(f16x8*)(dst + (size_t)((kb + j*8) >> 3) * 512 + r*8) = cvt8(a, b);
        }
      }
    }
  }
  // ---- startup barrier: the ONLY cache-maintaining release/acquire ----
  __syncthreads();
  if (tid == 0) {
    __hip_atomic_fetch_add(cnt0, 1u, __ATOMIC_RELEASE, __HIP_MEMORY_SCOPE_AGENT);
    int g = 0;
    while (aload32(cnt0) < 256u && g < 2000000) { __builtin_amdgcn_s_sleep(1); ++g; }
    (void)__hip_atomic_load(cnt0, __ATOMIC_ACQUIRE, __HIP_MEMORY_SCOPE_AGENT);
  }
  __syncthreads();

  // ---- per-thread constants / state ----
  const float blq = blin[cw + ra];                    // Q bias (one col per lane)
  float c0a = 0.f, c0b = 0.f, c1a = 0.f, c1b = 0.f;

  f16x8 h0p[16], h1cf[16];
  #pragma unroll
  for (int q_ = 0; q_ < 16; ++q_) { h0p[q_] = f16x8{}; h1cf[q_] = f16x8{}; }
  f16x8 xe[4], xo[4], xen[4], xon[4];
  f32x4 acce, acco;

  auto vwait = [&](uint32_t* base) {
    if (tid < 64) {
      int g = 0;
      for (;;) {
        uint32_t v = aload32(base + tid);
        if (__ballot(v != 0u) == ~0ull) break;
        if (++g > 1000000) break;
        __builtin_amdgcn_s_sleep(2);
      }
    }
    asm volatile("" ::: "memory");
    __syncthreads();
  };

  // fragment from staged quarter: row (0..63), kloc (0..127, 8-aligned)
  auto lfrag = [&](int row, int kloc) -> f16x8 {
    return *(const f16x8*)&hstg[kloc >> 3][row * 8];
  };
  // direct fragment from a t-slab: lane needs h[row][k..k+7]; k 8-aligned
  auto hfrag = [&](const f16* bs, int k) -> f16x8 {
    return *(const f16x8*)(bs + ((size_t)(k >> 3) * 512 + arow * 8));
  };
  // x fragment loads for step t -> (e[4], o[4])
  auto load_x = [&](int t, f16x8* e, f16x8* o) {
    if (PRE) {
      const f16* xb16 = xf16 + ((size_t)t*4 + m) * 16384;
      #pragma unroll
      for (int j = 0; j < 4; ++j) {
        e[j] = *(const f16x8*)(xb16 + (size_t)((j*64 + kg) >> 3) * 512 + arow*8);
        o[j] = *(const f16x8*)(xb16 + (size_t)((j*64 + 32 + kg) >> 3) * 512 + arow*8);
      }
    } else {
      const float* xb = states + ((size_t)(m*64 + arow) * TT + t) * 256;
      #pragma unroll
      for (int j = 0; j < 4; ++j) {
        f32x4 a0 = *(const f32x4*)(xb + j*64 + kg);
        f32x4 a1 = *(const f32x4*)(xb + j*64 + kg + 4);
        f32x4 b0 = *(const f32x4*)(xb + j*64 + 32 + kg);
        f32x4 b1 = *(const f32x4*)(xb + j*64 + 32 + kg + 4);
        e[j] = cvt8(a0, a1);
        o[j] = cvt8(b0, b1);
      }
    }
  };

  // ---- Q phase for tq: wait h1(tq), reg-prefetch slab, staged GEMM (remapped), softmax ----
  auto q_phase = [&](int tq) {
    float nzq[4][4];
    if (PRE) {
      const float* np0 = noise_pre + ((size_t)tq*256 + m*64 + crow) * 128 + cw + ra;
      #pragma unroll
      for (int mu2 = 0; mu2 < 4; ++mu2)
        #pragma unroll
        for (int r = 0; r < 4; ++r)
          nzq[mu2][r] = np0[(size_t)(mu2*16 + r) * 128];
    }
    vwait(flagsB + (size_t)(tq*4 + m) * 64);
    const f16* hb = h1blk + ((size_t)tq*4 + m) * 32768;
    // register-prefetch ALL 4 quarters (only quarter 0's latency is exposed)
    f16x8 qreg[8];
    #pragma unroll
    for (int q = 0; q < 4; ++q) {
      qreg[2*q]     = *(const f16x8*)(hb + q*8192 + tid*8);
      qreg[2*q + 1] = *(const f16x8*)(hb + q*8192 + 4096 + tid*8);
    }
    f32x4 accq[4] = {{0,0,0,0},{0,0,0,0},{0,0,0,0},{0,0,0,0}};
    #pragma unroll
    for (int q = 0; q < 4; ++q) {
      if (q) __syncthreads();                  // prior quarter's reads done
      *(f16x8*)&hstg[tid >> 6][(tid & 63) * 8]       = qreg[2*q];
      *(f16x8*)&hstg[8 + (tid >> 6)][(tid & 63) * 8] = qreg[2*q + 1];
      __syncthreads();
      // own-arow h1 frags (L1 part1 operands): chunks 2q, 2q+1
      h1cf[4*q]     = lfrag(arow, kg);
      h1cf[4*q + 1] = lfrag(arow, 32 + kg);
      h1cf[4*q + 2] = lfrag(arow, 64 + kg);
      h1cf[4*q + 3] = lfrag(arow, 96 + kg);
      // Q GEMM quarter: wave covers cols cw..cw+15 x all 64 rows
      #pragma unroll
      for (int jj = 0; jj < 2; ++jj) {
        const f16* wqp = Wlc + (size_t)(cw + ra) * 512 + (q*2 + jj) * 64;
        f16x8 bE = *(const f16x8*)(wqp + kg);
        f16x8 bO = *(const f16x8*)(wqp + 32 + kg);
        #pragma unroll
        for (int mu2 = 0; mu2 < 4; ++mu2) {
          f16x8 ae = lfrag(mu2*16 + ra, jj*64 + kg);
          f16x8 ao = lfrag(mu2*16 + ra, jj*64 + 32 + kg);
          accq[mu2] = __builtin_amdgcn_mfma_f32_16x16x32_f16(ae, bE, accq[mu2], 0, 0, 0);
          accq[mu2] = __builtin_amdgcn_mfma_f32_16x16x32_f16(ao, bO, accq[mu2], 0, 0, 0);
        }
      }
    }
    __syncthreads();                           // hstg reads done
    // softmax: C/D layout row = crow + r (within mu2 tile), col = ra
    #pragma unroll
    for (int mu2 = 0; mu2 < 4; ++mu2) {
      #pragma unroll
      for (int r = 0; r < 4; ++r) {
        const int row = mu2*16 + crow + r;
        const int col = cw + ra;
        float g;
        if (PRE) g = nzq[mu2][r];
        else g = gumbel_noise(((uint32_t)tq*256u + (uint32_t)(m*64 + row)) * 128u + (uint32_t)col, true);
        float v = (accq[mu2][r] + blq + g) * 10.0f;
        float mx = v;
        #pragma unroll
        for (int k_ = 1; k_ < 16; k_ <<= 1) mx = fmaxf(mx, __shfl_xor(mx, k_));
        float ex = __expf(v - mx);
        float sm = ex;
        #pragma unroll
        for (int k_ = 1; k_ < 16; k_ <<= 1) sm += __shfl_xor(sm, k_);
        ctl[row][col] = (f16)(ex * __builtin_amdgcn_rcpf(sm));
      }
    }
    __syncthreads();                           // ctl final
    if (tid < 128)
      out[((size_t)(m*64 + s) * TT + tq) * 128 + tid] = (float)ctl[s][tid];
  };

  // ---- layer epilogue: acc -> glds(overlay) -> cell -> coalesced publish + flag ----
  auto epilogue = [&](int L, float& ca, float& cb, f16* blkbuf, int t, uint32_t* slot) {
    f32x4 av = acce + acco;
    #pragma unroll
    for (int r = 0; r < 4; ++r)
      glds[mu*16 + crow + r][nu*16 + ra] = av[r];
    __syncthreads();
    if (tid < 256) {
      const int h2 = hc2 * 2;
      float ia = glds[erow][h2]      + bls[L][0][h2];
      float ib = glds[erow][h2 + 1]  + bls[L][0][h2 + 1];
      float fa = glds[erow][8 + h2]  + bls[L][1][h2];
      float fb = glds[erow][9 + h2]  + bls[L][1][h2 + 1];
      float ga = glds[erow][16 + h2] + bls[L][2][h2];
      float gb = glds[erow][17 + h2] + bls[L][2][h2 + 1];
      float oa = glds[erow][24 + h2] + bls[L][3][h2];
      float ob = glds[erow][25 + h2] + bls[L][3][h2 + 1];
      float cna = fsig(fa) * ca + fsig(ia) * ftanh(ga);
      float cnb = fsig(fb) * cb + fsig(ib) * ftanh(gb);
      ca = cna; cb = cnb;
      union { f16 h[2]; uint32_t u; } pk;
      pk.h[0] = (f16)(fsig(oa) * ftanh(cna));
      pk.h[1] = (f16)(fsig(ob) * ftanh(cnb));
      uint32_t* pb = (uint32_t*)(blkbuf + ((size_t)t*4 + m) * 32768 + (size_t)s * 512);
      astore32(pb + erow*4 + hc2, pk.u);
    }
    asm volatile("s_waitcnt vmcnt(0)" ::: "memory");
    __syncthreads();
    if (tid == 0) astore32(slot, 1u);
  };

  // ---- prologue: x(0) ----
  load_x(0, xe, xo);

  // ==================== main recurrence ====================
  for (int t = 0; t < TT; ++t) {
    // ---- L0 x + h0p chunks (register-only, covers hopB for Q(t-1)) ----
    acce = f32x4{0,0,0,0}; acco = f32x4{0,0,0,0};
    #pragma unroll
    for (int j = 0; j < 4; ++j)
      MFMA_PAIR(xe[j], xo[j], W0s[nu*16 + ra], j*64)
    #pragma unroll
    for (int j = 4; j < 12; ++j)
      MFMA_PAIR(h0p[2*(j-4)], h0p[2*(j-4) + 1], W0s[nu*16 + ra], j*64)

    // ---- Q(t-1): stages h1(t-1) slab (fills h1cf) + softmax -> ctl ----
    if (t > 0) q_phase(t - 1);

    // ---- L0 partB: ct chunks 12..13 from ctl ----
    {
      f16x8 ae = *(const f16x8*)&ctl[arow][kg];
      f16x8 ao = *(const f16x8*)&ctl[arow][32 + kg];
      MFMA_PAIR(ae, ao, W0s[nu*16 + ra], 768)
      ae = *(const f16x8*)&ctl[arow][64 + kg];
      ao = *(const f16x8*)&ctl[arow][96 + kg];
      MFMA_PAIR(ae, ao, W0s[nu*16 + ra], 832)
    }
    epilogue(0, c0a, c0b, h0blk, t, flagsA + (size_t)(t*4 + m)*64 + s);

    // ---- x(t+1) prefetch in the pub0 -> waitA window (hopA cover) ----
    {
      const int tn = (t + 1 < TT) ? t + 1 : t;
      load_x(tn, xen, xon);
    }

    // ---- L1 part1: chunks 0..7 (h1cf regs) ----
    acce = f32x4{0,0,0,0}; acco = f32x4{0,0,0,0};
    #pragma unroll
    for (int j = 0; j < 8; ++j)
      MFMA_PAIR(h1cf[2*j], h1cf[2*j + 1], W1s[nu*16 + ra], j*64)

    // ---- wait h0(t); DIRECT own-row frag loads (no LDS, no barriers) + L1 part2 ----
    vwait(flagsA + (size_t)(t*4 + m)*64);
    {
      const f16* hb0 = h0blk + ((size_t)t*4 + m) * 32768;
      #pragma unroll
      for (int j = 0; j < 8; ++j) {
        h0p[2*j]     = hfrag(hb0, j*64 + kg);
        h0p[2*j + 1] = hfrag(hb0, j*64 + 32 + kg);
      }
    }
    #pragma unroll
    for (int j = 8; j < 16; ++j)
      MFMA_PAIR(h0p[2*(j-8)], h0p[2*(j-8) + 1], W1s[nu*16 + ra], j*64)

    epilogue(1, c1a, c1b, h1blk, t, flagsB + (size_t)(t*4 + m)*64 + s);

    // rotate x registers
    #pragma unroll
    for (int j = 0; j < 4; ++j) { xe[j] = xen[j]; xo[j] = xon[j]; }
  }

  // ---- tail: Q for t = TT-1 ----
  q_phase(TT - 1);
}

// ---------------- host ----------------
extern "C" void kernel_launch(void* const* d_in, const int* in_sizes, int n_in,
                              void* d_out, int out_size, void* d_ws, size_t ws_size,
                              hipStream_t stream) {
  const float* states = (const float*)d_in[0];
  const float* Wih0 = (const float*)d_in[1];
  const float* Whh0 = (const float*)d_in[2];
  const float* bih0 = (const float*)d_in[3];
  const float* bhh0 = (const float*)d_in[4];
  const float* Wih1 = (const float*)d_in[5];
  const float* Whh1 = (const float*)d_in[6];
  const float* bih1 = (const float*)d_in[7];
  const float* bhh1 = (const float*)d_in[8];
  const float* Wlin = (const float*)d_in[9];
  const float* blin = (const float*)d_in[10];
  float* out = (float*)d_out;
  (void)in_sizes; (void)n_in; (void)out_size;

  char* ws = (char*)d_ws;
  uint32_t* flagsA = (uint32_t*)ws;                         // [512][4][64] u32 = 524,288 B
  uint32_t* flagsB = (uint32_t*)(ws + 524288);              // 524,288 B
  uint32_t* cnt0   = (uint32_t*)(ws + 1048576);             // 256 B pad
  const size_t cnt_bytes = 1048832;
  f16* Wlc = (f16*)(ws + cnt_bytes);                        // 131,072 B
  char* p = ws + cnt_bytes + 131072;

  f16* h0b = (f16*)p;                                       // 512*4*32768 f16 = 134,217,728 B
  f16* h1b = (f16*)(p + 134217728ull);
  float* noise = (float*)(p + 2ull*134217728);              // 67,108,864 B
  f16* xf16 = (f16*)(p + 2ull*134217728 + 67108864);        // 67,108,864 B

  const size_t need1 = cnt_bytes + 131072 + 2ull*134217728;              // ~269.6 MB
  const size_t need2 = need1 + 2ull*67108864;                            // ~403.8 MB

  hipMemsetAsync(ws, 0, cnt_bytes, stream);
  if (ws_size >= need2) {
    persistent_kernel<true><<<256, 512, 0, stream>>>(
        states, Wih0, Whh0, bih0, bhh0, Wih1, Whh1, bih1, bhh1, Wlin, blin,
        out, cnt0, flagsA, flagsB, h0b, h1b, Wlc, noise, xf16);
  } else {
    persistent_kernel<false><<<256, 512, 0, stream>>>(
        states, Wih0, Whh0, bih0, bhh0, Wih1, Whh1, bih1, bhh1, Wlin, blin,
        out, cnt0, flagsA, flagsB, h0b, h1b, Wlc, nullptr, nullptr);
  }
}